// Round 3
// baseline (446.712 us; speedup 1.0000x reference)
//
#include <hip/hip_runtime.h>
#include <hip/hip_bf16.h>
#include <math.h>

using bf16 = __hip_bfloat16;

static constexpr int Bn = 4;
static constexpr int Tn = 2048;
static constexpr int Dn = 1024;

typedef __attribute__((ext_vector_type(8))) short bf16x8;
typedef __attribute__((ext_vector_type(4))) float f32x4;

__device__ __forceinline__ float ldf(float v) { return v; }
__device__ __forceinline__ float ldf(bf16 v) { return __bfloat162float(v); }
__device__ __forceinline__ bf16 f2b(float v) { return __float2bfloat16(v); }

template <typename T> __device__ __forceinline__ T from_float(float v);
template <> __device__ __forceinline__ float from_float<float>(float v) { return v; }
template <> __device__ __forceinline__ bf16 from_float<bf16>(float v) { return f2b(v); }

// async global->LDS, 16B per lane. LDS dest must be wave-uniform base; HW scatters +lane*16.
__device__ __forceinline__ void async_copy16(const bf16* g, bf16* l) {
    __builtin_amdgcn_global_load_lds(
        (const __attribute__((address_space(1))) void*)g,
        (__attribute__((address_space(3))) void*)l,
        16, 0, 0);
}

// ---------------------------------------------------------------------------
// Generic NT GEMM: C[m,n] = sum_k A[m,k] * Bm[n,k]  (both row-major bf16, ld = K)
// mode 0: full; mode 1: skip blocks with bn>bm (causal scores);
// mode 2: K-loop truncated at (bm+1)*128 (causal PV).
// Epilogue: + bias[n] (fp32, optional), ReLU (template), + res (optional).
// 128x128 tile, BK=32, 4 waves (2x2), each wave 4x4 tiles of 16x16x32 bf16 MFMA.
// ---------------------------------------------------------------------------
template <typename OutT, typename ResT, bool RELU>
__global__ __launch_bounds__(256, 2) void gemm_nt(
    const bf16* __restrict__ A, const bf16* __restrict__ Bm,
    OutT* __restrict__ C, const float* __restrict__ bias,
    const ResT* __restrict__ res,
    int M, int N, int K,
    long sA, long sB, long sC, int mode)
{
    const int bm = blockIdx.y, bn = blockIdx.x, bz = blockIdx.z;
    if (mode == 1 && bn > bm) return;
    const int kmax = (mode == 2) ? (((bm + 1) * 128 < K) ? (bm + 1) * 128 : K) : K;

    const bf16* Ab = A + (size_t)bz * sA;
    const bf16* Bb = Bm + (size_t)bz * sB;

    __shared__ __align__(16) bf16 As[128 * 32];
    __shared__ __align__(16) bf16 Bs[128 * 32];

    const int tid = threadIdx.x;
    const int wave = tid >> 6;
    const int lane = tid & 63;
    const int wm = wave >> 1;   // 0..1
    const int wn = wave & 1;    // 0..1

    f32x4 acc[4][4] = {};

    // staging: each wave fills 2 chunks of 1KB (16 rows x 32 cols bf16) per tile
    const int lr = lane >> 2;          // row within chunk
    const int lc = (lane & 3) * 8;     // col offset (elements)
    const int c0 = wave * 2, c1 = c0 + 1;

    const bf16* gA0 = Ab + (size_t)(bm * 128 + c0 * 16 + lr) * K + lc;
    const bf16* gA1 = Ab + (size_t)(bm * 128 + c1 * 16 + lr) * K + lc;
    const bf16* gB0 = Bb + (size_t)(bn * 128 + c0 * 16 + lr) * K + lc;
    const bf16* gB1 = Bb + (size_t)(bn * 128 + c1 * 16 + lr) * K + lc;

    bf16* lA0 = &As[c0 * 512];
    bf16* lA1 = &As[c1 * 512];
    bf16* lB0 = &Bs[c0 * 512];
    bf16* lB1 = &Bs[c1 * 512];

    const int arow = lane & 15;          // A/B fragment row
    const int kq = (lane >> 4) * 8;      // k offset within BK=32

    for (int k0 = 0; k0 < kmax; k0 += 32) {
        async_copy16(gA0 + k0, lA0);
        async_copy16(gA1 + k0, lA1);
        async_copy16(gB0 + k0, lB0);
        async_copy16(gB1 + k0, lB1);
        __syncthreads();   // barrier drains vmcnt -> LDS visible

        bf16x8 af[4], bfm[4];
#pragma unroll
        for (int t = 0; t < 4; ++t) {
            af[t]  = *(const bf16x8*)&As[(wm * 64 + t * 16 + arow) * 32 + kq];
            bfm[t] = *(const bf16x8*)&Bs[(wn * 64 + t * 16 + arow) * 32 + kq];
        }
#pragma unroll
        for (int mt = 0; mt < 4; ++mt)
#pragma unroll
            for (int nt = 0; nt < 4; ++nt)
                acc[mt][nt] = __builtin_amdgcn_mfma_f32_16x16x32_bf16(
                    af[mt], bfm[nt], acc[mt][nt], 0, 0, 0);
        __syncthreads();   // protect LDS before next stage
    }

    // epilogue: C/D layout col = lane&15, row = (lane>>4)*4 + reg
    OutT* Cb = C + (size_t)bz * sC;
    const ResT* Rb = res ? (res + (size_t)bz * sC) : nullptr;
    const int rowBase = bm * 128 + wm * 64;
    const int colBase = bn * 128 + wn * 64;
    const int qrow = (lane >> 4) * 4;
    const int ccol = lane & 15;

#pragma unroll
    for (int mt = 0; mt < 4; ++mt) {
#pragma unroll
        for (int nt = 0; nt < 4; ++nt) {
            const int cc = colBase + nt * 16 + ccol;
            const float bv = bias ? bias[cc] : 0.0f;
#pragma unroll
            for (int r = 0; r < 4; ++r) {
                const int rr = rowBase + mt * 16 + qrow + r;
                float v = acc[mt][nt][r] + bv;
                if (RELU) v = fmaxf(v, 0.0f);
                if (Rb) v += ldf(Rb[(size_t)rr * N + cc]);
                Cb[(size_t)rr * N + cc] = from_float<OutT>(v);
            }
        }
    }
}

// ---------------------------------------------------------------------------
// LayerNorm (faithfully buggy): out = (x - mean/sqrt(var_unbiased)) * gamma + beta
// One block (256 thr) per row of D=1024. Input fp32, params fp32, output bf16.
// ---------------------------------------------------------------------------
__global__ __launch_bounds__(256) void ln_kernel(
    const float* __restrict__ x, const float* __restrict__ gamma,
    const float* __restrict__ beta, bf16* __restrict__ out)
{
    const int row = blockIdx.x;
    const int tid = threadIdx.x;
    const float* xr = x + (size_t)row * Dn;
    bf16* orow = out + (size_t)row * Dn;

    float v[4];
    float s = 0.f, sq = 0.f;
#pragma unroll
    for (int i = 0; i < 4; ++i) {
        const float val = xr[tid + 256 * i];
        v[i] = val; s += val; sq += val * val;
    }
#pragma unroll
    for (int o = 32; o > 0; o >>= 1) {
        s += __shfl_down(s, o);
        sq += __shfl_down(sq, o);
    }
    __shared__ float red[2][4];
    const int lane = tid & 63, w = tid >> 6;
    if (lane == 0) { red[0][w] = s; red[1][w] = sq; }
    __syncthreads();
    s  = red[0][0] + red[0][1] + red[0][2] + red[0][3];
    sq = red[1][0] + red[1][1] + red[1][2] + red[1][3];
    const float mean = s / (float)Dn;
    const float var = (sq - s * s / (float)Dn) / (float)(Dn - 1);
    const float coef = mean * rsqrtf(var);
#pragma unroll
    for (int i = 0; i < 4; ++i) {
        const int j = tid + 256 * i;
        orow[j] = f2b((v[i] - coef) * gamma[j] + beta[j]);
    }
}

// ---------------------------------------------------------------------------
// Causal softmax over fp32 scores; writes bf16 probs (zeros beyond the diagonal).
// One block per (b, i) row; valid length L = i+1; scale = 1/sqrt(D).
// ---------------------------------------------------------------------------
__global__ __launch_bounds__(256) void softmax_kernel(
    const float* __restrict__ S, bf16* __restrict__ P)
{
    const int r = blockIdx.x;
    const int b = r / Tn, i = r % Tn;
    const float* srow = S + (size_t)b * Tn * Tn + (size_t)i * Tn;
    bf16* prow = P + (size_t)b * Tn * Tn + (size_t)i * Tn;
    const int L = i + 1;
    const float scale = 0.03125f;  // 1/sqrt(1024)
    const int tid = threadIdx.x;
    const int lane = tid & 63, w = tid >> 6;
    __shared__ float rmx[4], rsum[4];

    float mx = -3.0e38f;
    for (int j = tid; j < L; j += 256) mx = fmaxf(mx, srow[j] * scale);
#pragma unroll
    for (int o = 32; o > 0; o >>= 1) mx = fmaxf(mx, __shfl_down(mx, o));
    if (lane == 0) rmx[w] = mx;
    __syncthreads();
    mx = fmaxf(fmaxf(rmx[0], rmx[1]), fmaxf(rmx[2], rmx[3]));

    float sum = 0.f;
    for (int j = tid; j < L; j += 256) sum += __expf(srow[j] * scale - mx);
#pragma unroll
    for (int o = 32; o > 0; o >>= 1) sum += __shfl_down(sum, o);
    if (lane == 0) rsum[w] = sum;
    __syncthreads();
    sum = rsum[0] + rsum[1] + rsum[2] + rsum[3];
    const float inv = 1.0f / sum;

    for (int j = tid; j < Tn; j += 256) {
        const float p = (j < L) ? __expf(srow[j] * scale - mx) * inv : 0.0f;
        prow[j] = f2b(p);
    }
}

// ---------------------------------------------------------------------------
// Transpose with dtype convert to bf16: out[c, r] = bf16(in[r, c]); batched z.
// ---------------------------------------------------------------------------
template <typename InT>
__global__ __launch_bounds__(256) void transpose_kernel(
    const InT* __restrict__ in, bf16* __restrict__ out,
    int rows, int cols, long inStride, long outStride)
{
    __shared__ bf16 tile[32][33];
    const int z = blockIdx.z;
    const InT* src = in + (size_t)z * inStride;
    bf16* dst = out + (size_t)z * outStride;
    const int c0 = blockIdx.x * 32, r0 = blockIdx.y * 32;
    const int tx = threadIdx.x & 31;
    const int ty = threadIdx.x >> 5;  // 0..7
#pragma unroll
    for (int dy = 0; dy < 32; dy += 8)
        tile[ty + dy][tx] = f2b(ldf(src[(size_t)(r0 + ty + dy) * cols + (c0 + tx)]));
    __syncthreads();
#pragma unroll
    for (int dy = 0; dy < 32; dy += 8)
        dst[(size_t)(c0 + ty + dy) * rows + (r0 + tx)] = tile[tx][ty + dy];
}

extern "C" void kernel_launch(void* const* d_in, const int* in_sizes, int n_in,
                              void* d_out, int out_size, void* d_ws, size_t ws_size,
                              hipStream_t stream) {
    const float* x      = (const float*)d_in[0];
    const float* gamma1 = (const float*)d_in[1];
    const float* beta1  = (const float*)d_in[2];
    const float* w_q    = (const float*)d_in[3];
    const float* w_k    = (const float*)d_in[4];
    const float* w_v    = (const float*)d_in[5];
    const float* gamma2 = (const float*)d_in[6];
    const float* beta2  = (const float*)d_in[7];
    const float* W1     = (const float*)d_in[8];
    const float* b1     = (const float*)d_in[9];
    const float* W2     = (const float*)d_in[10];
    const float* b2     = (const float*)d_in[11];
    float* out = (float*)d_out;   // fp32 output buffer (compared in bf16 space)

    char* ws = (char*)d_ws;
    size_t off = 0;
    auto alloc = [&](size_t bytes) {
        char* p = ws + off;
        off += (bytes + 255) & ~(size_t)255;
        return p;
    };
    const size_t BT = (size_t)Bn * Tn;
    bf16* h   = (bf16*)alloc(BT * Dn * 2);            // LN1 out; reused as h2
    bf16* q   = (bf16*)alloc(BT * Dn * 2);            // Q; reused as mid
    bf16* k   = (bf16*)alloc(BT * Dn * 2);
    bf16* v   = (bf16*)alloc(BT * Dn * 2);
    bf16* vt  = (bf16*)alloc(BT * Dn * 2);            // V^T per batch [D, T]
    bf16* wtq = (bf16*)alloc((size_t)Dn * Dn * 2);
    bf16* wtk = (bf16*)alloc((size_t)Dn * Dn * 2);
    bf16* wtv = (bf16*)alloc((size_t)Dn * Dn * 2);
    bf16* wt1 = (bf16*)alloc((size_t)Dn * Dn * 2);
    bf16* wt2 = (bf16*)alloc((size_t)Dn * Dn * 2);
    float* S  = (float*)alloc((size_t)Bn * Tn * Tn * 4);  // 64 MB (dead after softmax)
    bf16* P   = (bf16*)alloc((size_t)Bn * Tn * Tn * 2);   // 32 MB
    float* y  = S;   // overlay: y (32 MB) reuses S space (S dead after softmax)
    bf16* h2  = h;   // reuse (h dead after QKV)
    bf16* mid = q;   // reuse (q dead after scores)

    const dim3 blk(256);
    const long TD = (long)Tn * Dn;
    const long TT = (long)Tn * Tn;

    // weight transposes + fp32->bf16 convert: W[k,d] -> WT[d,k]
    transpose_kernel<float><<<dim3(32, 32, 1), blk, 0, stream>>>(w_q, wtq, Dn, Dn, 0, 0);
    transpose_kernel<float><<<dim3(32, 32, 1), blk, 0, stream>>>(w_k, wtk, Dn, Dn, 0, 0);
    transpose_kernel<float><<<dim3(32, 32, 1), blk, 0, stream>>>(w_v, wtv, Dn, Dn, 0, 0);
    transpose_kernel<float><<<dim3(32, 32, 1), blk, 0, stream>>>(W1, wt1, Dn, Dn, 0, 0);
    transpose_kernel<float><<<dim3(32, 32, 1), blk, 0, stream>>>(W2, wt2, Dn, Dn, 0, 0);

    // LN1: x -> h (bf16)
    ln_kernel<<<dim3((unsigned)BT), blk, 0, stream>>>(x, gamma1, beta1, h);

    // QKV: [BT,1024] @ [1024,1024]
    gemm_nt<bf16, float, false><<<dim3(Dn / 128, BT / 128, 1), blk, 0, stream>>>(
        h, wtq, q, nullptr, nullptr, (int)BT, Dn, Dn, 0, 0, 0, 0);
    gemm_nt<bf16, float, false><<<dim3(Dn / 128, BT / 128, 1), blk, 0, stream>>>(
        h, wtk, k, nullptr, nullptr, (int)BT, Dn, Dn, 0, 0, 0, 0);
    gemm_nt<bf16, float, false><<<dim3(Dn / 128, BT / 128, 1), blk, 0, stream>>>(
        h, wtv, v, nullptr, nullptr, (int)BT, Dn, Dn, 0, 0, 0, 0);

    // V^T per batch: [T,D] -> [D,T]
    transpose_kernel<bf16><<<dim3(Dn / 32, Tn / 32, Bn), blk, 0, stream>>>(v, vt, Tn, Dn, TD, TD);

    // scores = q @ k^T (batched, causal block-skip), fp32 out
    gemm_nt<float, float, false><<<dim3(Tn / 128, Tn / 128, Bn), blk, 0, stream>>>(
        q, k, S, nullptr, nullptr, Tn, Tn, Dn, TD, TD, TT, 1);

    // softmax -> P (bf16, zero above diagonal)
    softmax_kernel<<<dim3((unsigned)BT), blk, 0, stream>>>(S, P);

    // y = P @ V + x (batched, K truncated at diagonal), fp32 out; res = x (fp32)
    gemm_nt<float, float, false><<<dim3(Dn / 128, Tn / 128, Bn), blk, 0, stream>>>(
        P, vt, y, nullptr, x, Tn, Dn, Tn, TT, TD, TD, 2);

    // LN2: y -> h2 (bf16)
    ln_kernel<<<dim3((unsigned)BT), blk, 0, stream>>>(y, gamma2, beta2, h2);

    // mid = relu(h2 @ W1 + b1)
    gemm_nt<bf16, float, true><<<dim3(Dn / 128, BT / 128, 1), blk, 0, stream>>>(
        h2, wt1, mid, b1, nullptr, (int)BT, Dn, Dn, 0, 0, 0, 0);

    // out = mid @ W2 + b2 + y  (fp32 output)
    gemm_nt<float, float, false><<<dim3(Dn / 128, BT / 128, 1), blk, 0, stream>>>(
        mid, wt2, out, b2, y, (int)BT, Dn, Dn, 0, 0, 0, 0);
}

// Round 4
// 423.751 us; speedup vs baseline: 1.0542x; 1.0542x over previous
//
#include <hip/hip_runtime.h>
#include <hip/hip_bf16.h>
#include <math.h>

using bf16 = __hip_bfloat16;

static constexpr int Bn = 4;
static constexpr int Tn = 2048;
static constexpr int Dn = 1024;

typedef __attribute__((ext_vector_type(8))) short bf16x8;
typedef __attribute__((ext_vector_type(4))) float f32x4;

__device__ __forceinline__ float ldf(float v) { return v; }
__device__ __forceinline__ float ldf(bf16 v) { return __bfloat162float(v); }
__device__ __forceinline__ bf16 f2b(float v) { return __float2bfloat16(v); }
__device__ __forceinline__ float b2f(short s) {
    return __uint_as_float(((unsigned)(unsigned short)s) << 16);
}
__device__ __forceinline__ short f2bs(float v) {
    bf16 t = __float2bfloat16(v);
    return *reinterpret_cast<short*>(&t);
}

template <typename T> __device__ __forceinline__ T from_float(float v);
template <> __device__ __forceinline__ float from_float<float>(float v) { return v; }
template <> __device__ __forceinline__ bf16 from_float<bf16>(float v) { return f2b(v); }

__device__ __forceinline__ void load4(const float* p, float* v) {
    const float4 t = *(const float4*)p;
    v[0] = t.x; v[1] = t.y; v[2] = t.z; v[3] = t.w;
}
__device__ __forceinline__ void load4(const bf16* p, float* v) {
    const short4 t = *(const short4*)p;
    v[0] = b2f(t.x); v[1] = b2f(t.y); v[2] = b2f(t.z); v[3] = b2f(t.w);
}

// async global->LDS, 16B per lane; LDS dest wave-uniform base, HW scatters +lane*16.
__device__ __forceinline__ void async_copy16(const bf16* g, bf16* l) {
    __builtin_amdgcn_global_load_lds(
        (const __attribute__((address_space(1))) void*)g,
        (__attribute__((address_space(3))) void*)l,
        16, 0, 0);
}

// ---------------------------------------------------------------------------
// Generic NT GEMM: C[m,n] = sum_k A[m,k]*B[n,k], bf16 inputs, explicit ld's.
// Tile BM x BN, BK=32, 4 waves. BM=128: waves 2x2 (wave tile 64x64, acc 4x4).
// BM=64: waves 1x4 (wave tile 64x32, acc 4x2).
// mode 0: full; 1: skip blocks fully above diagonal (bn*BN > bm*BM+BM-1);
// 2: K truncated at bm*BM+BM (causal PV).
// Epilogue: +bias[n] (fp32), optional ReLU, + res (ResT), write OutT.
// ---------------------------------------------------------------------------
template <int BM, int BN, typename OutT, typename ResT, bool RELU>
__global__ __launch_bounds__(256, 4) void gemm_nt(
    const bf16* __restrict__ A, const bf16* __restrict__ Bm,
    OutT* __restrict__ C, const float* __restrict__ bias,
    const ResT* __restrict__ res,
    int M, int N, int K, int lda, int ldb, int ldc,
    long sA, long sB, long sC, long sR, int mode)
{
    const int bm = blockIdx.y, bn = blockIdx.x, bz = blockIdx.z;
    if (mode == 1 && bn * BN > bm * BM + (BM - 1)) return;
    const int kend = bm * BM + BM;
    const int kmax = (mode == 2) ? (kend < K ? kend : K) : K;

    const bf16* Ab = A + (size_t)bz * sA;
    const bf16* Bb = Bm + (size_t)bz * sB;

    constexpr int WROWS = BM / 64;          // 2 or 1
    constexpr int WCOLS = 4 / WROWS;        // 2 or 4
    constexpr int TM = 64;
    constexpr int TN = BN / WCOLS;          // 64 or 32
    constexpr int MT = TM / 16;             // 4
    constexpr int NT = TN / 16;             // 4 or 2
    constexpr int nA = BM / 16;             // 1KB chunks in A tile
    constexpr int nB = BN / 16;

    __shared__ __align__(16) bf16 As[BM * 32];
    __shared__ __align__(16) bf16 Bs[BN * 32];

    const int tid = threadIdx.x;
    const int wave = tid >> 6;
    const int lane = tid & 63;
    const int wm = wave / WCOLS;
    const int wn = wave % WCOLS;

    f32x4 acc[MT][NT] = {};

    // staging: chunk c covers rows [c*16, c*16+16) x 32 cols = 1KB
    const int lr = lane >> 2;
    const int lc = (lane & 3) * 8;
    const bf16* gAc[nA / 4]; bf16* lAc[nA / 4];
    const bf16* gBc[nB / 4]; bf16* lBc[nB / 4];
#pragma unroll
    for (int i = 0; i < nA / 4; ++i) {
        const int c = wave + 4 * i;
        gAc[i] = Ab + (size_t)(bm * BM + c * 16 + lr) * lda + lc;
        lAc[i] = &As[c * 512];
    }
#pragma unroll
    for (int i = 0; i < nB / 4; ++i) {
        const int c = wave + 4 * i;
        gBc[i] = Bb + (size_t)(bn * BN + c * 16 + lr) * ldb + lc;
        lBc[i] = &Bs[c * 512];
    }

    const int arow = lane & 15;
    const int kq = (lane >> 4) * 8;

    for (int k0 = 0; k0 < kmax; k0 += 32) {
#pragma unroll
        for (int i = 0; i < nA / 4; ++i) async_copy16(gAc[i] + k0, lAc[i]);
#pragma unroll
        for (int i = 0; i < nB / 4; ++i) async_copy16(gBc[i] + k0, lBc[i]);
        __syncthreads();

        bf16x8 af[MT], bfm[NT];
#pragma unroll
        for (int t = 0; t < MT; ++t)
            af[t] = *(const bf16x8*)&As[(wm * TM + t * 16 + arow) * 32 + kq];
#pragma unroll
        for (int t = 0; t < NT; ++t)
            bfm[t] = *(const bf16x8*)&Bs[(wn * TN + t * 16 + arow) * 32 + kq];
#pragma unroll
        for (int mt = 0; mt < MT; ++mt)
#pragma unroll
            for (int nt = 0; nt < NT; ++nt)
                acc[mt][nt] = __builtin_amdgcn_mfma_f32_16x16x32_bf16(
                    af[mt], bfm[nt], acc[mt][nt], 0, 0, 0);
        __syncthreads();
    }

    // epilogue: C/D layout col = lane&15, row = (lane>>4)*4 + reg
    OutT* Cb = C + (size_t)bz * sC;
    const ResT* Rb = res ? (res + (size_t)bz * sR) : nullptr;
    const int rowBase = bm * BM + wm * TM;
    const int colBase = bn * BN + wn * TN;
    const int qrow = (lane >> 4) * 4;
    const int ccol = lane & 15;

#pragma unroll
    for (int mt = 0; mt < MT; ++mt) {
#pragma unroll
        for (int nt = 0; nt < NT; ++nt) {
            const int cc = colBase + nt * 16 + ccol;
            const float bv = bias ? bias[cc] : 0.0f;
#pragma unroll
            for (int r = 0; r < 4; ++r) {
                const int rr = rowBase + mt * 16 + qrow + r;
                float v = acc[mt][nt][r] + bv;
                if (RELU) v = fmaxf(v, 0.0f);
                if (Rb) v += ldf(Rb[(size_t)rr * ldc + cc]);
                Cb[(size_t)rr * ldc + cc] = from_float<OutT>(v);
            }
        }
    }
}

// ---------------------------------------------------------------------------
// LayerNorm (faithfully buggy): out = (x - mean/sqrt(var_unbiased))*gamma + beta
// One 256-thr block per row; each thread owns 4 consecutive elements.
// ---------------------------------------------------------------------------
template <typename InT>
__global__ __launch_bounds__(256) void ln_kernel(
    const InT* __restrict__ x, const float* __restrict__ gamma,
    const float* __restrict__ beta, bf16* __restrict__ out)
{
    const int row = blockIdx.x;
    const int tid = threadIdx.x;
    const int j = tid * 4;
    const InT* xr = x + (size_t)row * Dn;

    float v[4];
    load4(xr + j, v);
    float s = v[0] + v[1] + v[2] + v[3];
    float sq = v[0] * v[0] + v[1] * v[1] + v[2] * v[2] + v[3] * v[3];
#pragma unroll
    for (int o = 32; o > 0; o >>= 1) {
        s += __shfl_down(s, o);
        sq += __shfl_down(sq, o);
    }
    __shared__ float red[2][4];
    const int lane = tid & 63, w = tid >> 6;
    if (lane == 0) { red[0][w] = s; red[1][w] = sq; }
    __syncthreads();
    s  = red[0][0] + red[0][1] + red[0][2] + red[0][3];
    sq = red[1][0] + red[1][1] + red[1][2] + red[1][3];
    const float mean = s / (float)Dn;
    const float var = (sq - s * s / (float)Dn) / (float)(Dn - 1);
    const float coef = mean * rsqrtf(var);

    const float4 g = *(const float4*)(gamma + j);
    const float4 be = *(const float4*)(beta + j);
    short4 o;
    o.x = f2bs((v[0] - coef) * g.x + be.x);
    o.y = f2bs((v[1] - coef) * g.y + be.y);
    o.z = f2bs((v[2] - coef) * g.z + be.z);
    o.w = f2bs((v[3] - coef) * g.w + be.w);
    *(short4*)(out + (size_t)row * Dn + j) = o;
}

// ---------------------------------------------------------------------------
// Causal softmax, bf16 in / bf16 out. One block per row; thread owns 8 elems.
// ---------------------------------------------------------------------------
__global__ __launch_bounds__(256) void softmax_kernel(
    const bf16* __restrict__ S, bf16* __restrict__ P)
{
    const int r = blockIdx.x;
    const int b = r >> 11, i = r & (Tn - 1);
    const bf16* srow = S + ((size_t)b * Tn + i) * Tn;
    bf16* prow = P + ((size_t)b * Tn + i) * Tn;
    const int L = i + 1;
    const float scale = 0.03125f;  // 1/sqrt(1024)
    const int tid = threadIdx.x;
    const int j0 = tid * 8;
    const int lane = tid & 63, w = tid >> 6;

    const bf16x8 sv = *(const bf16x8*)(srow + j0);
    float v[8];
#pragma unroll
    for (int e = 0; e < 8; ++e)
        v[e] = (j0 + e < L) ? b2f(sv[e]) * scale : -INFINITY;

    float mx = v[0];
#pragma unroll
    for (int e = 1; e < 8; ++e) mx = fmaxf(mx, v[e]);
#pragma unroll
    for (int o = 32; o > 0; o >>= 1) mx = fmaxf(mx, __shfl_down(mx, o));
    __shared__ float rmx[4], rsum[4];
    if (lane == 0) rmx[w] = mx;
    __syncthreads();
    mx = fmaxf(fmaxf(rmx[0], rmx[1]), fmaxf(rmx[2], rmx[3]));

    float p[8], sum = 0.f;
#pragma unroll
    for (int e = 0; e < 8; ++e) { p[e] = __expf(v[e] - mx); sum += p[e]; }
#pragma unroll
    for (int o = 32; o > 0; o >>= 1) sum += __shfl_down(sum, o);
    if (lane == 0) rsum[w] = sum;
    __syncthreads();
    sum = rsum[0] + rsum[1] + rsum[2] + rsum[3];
    const float inv = 1.0f / sum;

    bf16x8 pv;
#pragma unroll
    for (int e = 0; e < 8; ++e) pv[e] = f2bs(p[e] * inv);
    *(bf16x8*)(prow + j0) = pv;
}

// ---------------------------------------------------------------------------
// Transpose + convert to bf16: out[c*ldo + r] = bf16(in[r*ldi + c]); batched z.
// ---------------------------------------------------------------------------
template <typename InT>
__global__ __launch_bounds__(256) void transpose_kernel(
    const InT* __restrict__ in, bf16* __restrict__ out,
    int ldi, int ldo, long inStride, long outStride)
{
    __shared__ bf16 tile[32][33];
    const int z = blockIdx.z;
    const InT* src = in + (size_t)z * inStride;
    bf16* dst = out + (size_t)z * outStride;
    const int c0 = blockIdx.x * 32, r0 = blockIdx.y * 32;
    const int tx = threadIdx.x & 31;
    const int ty = threadIdx.x >> 5;
#pragma unroll
    for (int dy = 0; dy < 32; dy += 8)
        tile[ty + dy][tx] = f2b(ldf(src[(size_t)(r0 + ty + dy) * ldi + (c0 + tx)]));
    __syncthreads();
#pragma unroll
    for (int dy = 0; dy < 32; dy += 8)
        dst[(size_t)(c0 + ty + dy) * ldo + (r0 + tx)] = tile[tx][ty + dy];
}

extern "C" void kernel_launch(void* const* d_in, const int* in_sizes, int n_in,
                              void* d_out, int out_size, void* d_ws, size_t ws_size,
                              hipStream_t stream) {
    const float* x      = (const float*)d_in[0];
    const float* gamma1 = (const float*)d_in[1];
    const float* beta1  = (const float*)d_in[2];
    const float* w_q    = (const float*)d_in[3];
    const float* w_k    = (const float*)d_in[4];
    const float* w_v    = (const float*)d_in[5];
    const float* gamma2 = (const float*)d_in[6];
    const float* beta2  = (const float*)d_in[7];
    const float* W1     = (const float*)d_in[8];
    const float* b1     = (const float*)d_in[9];
    const float* W2     = (const float*)d_in[10];
    const float* b2     = (const float*)d_in[11];
    float* out = (float*)d_out;   // fp32 output buffer (compared in bf16 space)

    char* ws = (char*)d_ws;
    size_t off = 0;
    auto alloc = [&](size_t bytes) {
        char* p = ws + off;
        off += (bytes + 255) & ~(size_t)255;
        return p;
    };
    const size_t BT = (size_t)Bn * Tn;
    bf16* h     = (bf16*)alloc(BT * Dn * 2);               // 16 MB; reused as h2
    bf16* qkv   = (bf16*)alloc(BT * 3 * Dn * 2);           // 48 MB [8192,3072]
    bf16* vt    = (bf16*)alloc(BT * Dn * 2);               // 16 MB [4][1024,2048]
    bf16* wqkvt = (bf16*)alloc((size_t)3 * Dn * Dn * 2);   //  6 MB [3072,1024]
    bf16* wt1   = (bf16*)alloc((size_t)Dn * Dn * 2);       //  2 MB
    bf16* wt2   = (bf16*)alloc((size_t)Dn * Dn * 2);       //  2 MB
    bf16* S     = (bf16*)alloc((size_t)Bn * Tn * Tn * 2);  // 32 MB
    bf16* P     = (bf16*)alloc((size_t)Bn * Tn * Tn * 2);  // 32 MB
    bf16* y     = S;            // overlay: S dead after softmax (y = 16 MB)
    bf16* h2    = h;            // h dead after QKV
    bf16* mid   = qkv;          // qkv dead after PV

    const dim3 blk(256);
    const long TD   = (long)Tn * Dn;
    const long TT   = (long)Tn * Tn;
    const long TD3  = (long)Tn * 3 * Dn;

    // weight transposes + fp32->bf16: W[k,d] -> WT[d,k]; QKV concatenated.
    transpose_kernel<float><<<dim3(32, 32, 1), blk, 0, stream>>>(w_q, wqkvt,                Dn, Dn, 0, 0);
    transpose_kernel<float><<<dim3(32, 32, 1), blk, 0, stream>>>(w_k, wqkvt + 1024 * 1024,  Dn, Dn, 0, 0);
    transpose_kernel<float><<<dim3(32, 32, 1), blk, 0, stream>>>(w_v, wqkvt + 2048 * 1024,  Dn, Dn, 0, 0);
    transpose_kernel<float><<<dim3(32, 32, 1), blk, 0, stream>>>(W1, wt1, Dn, Dn, 0, 0);
    transpose_kernel<float><<<dim3(32, 32, 1), blk, 0, stream>>>(W2, wt2, Dn, Dn, 0, 0);

    // LN1: x -> h (bf16)
    ln_kernel<float><<<dim3((unsigned)BT), blk, 0, stream>>>(x, gamma1, beta1, h);

    // merged QKV: [8192,1024] @ [1024,3072] -> qkv [8192,3072]
    gemm_nt<128, 128, bf16, float, false><<<dim3(24, 64, 1), blk, 0, stream>>>(
        h, wqkvt, qkv, nullptr, nullptr,
        (int)BT, 3 * Dn, Dn, Dn, Dn, 3 * Dn, 0, 0, 0, 0, 0);

    // V^T per batch: v = qkv cols [2048,3072) -> vt [1024,2048]
    transpose_kernel<bf16><<<dim3(32, 64, Bn), blk, 0, stream>>>(
        qkv + 2048, vt, 3 * Dn, Tn, TD3, TD);

    // scores = q @ k^T (batched, causal block-skip), bf16 out
    gemm_nt<64, 128, bf16, float, false><<<dim3(16, 32, Bn), blk, 0, stream>>>(
        qkv, qkv + 1024, S, nullptr, nullptr,
        Tn, Tn, Dn, 3 * Dn, 3 * Dn, Tn, TD3, TD3, TT, 0, 1);

    // softmax -> P (bf16, zeros above diagonal)
    softmax_kernel<<<dim3((unsigned)BT), blk, 0, stream>>>(S, P);

    // y = P @ V + x (batched, K truncated), bf16 out, res = x (fp32)
    gemm_nt<64, 128, bf16, float, false><<<dim3(8, 32, Bn), blk, 0, stream>>>(
        P, vt, y, nullptr, x,
        Tn, Dn, Tn, Tn, Tn, Dn, TT, TD, TD, TD, 2);

    // LN2: y (bf16) -> h2 (bf16)
    ln_kernel<bf16><<<dim3((unsigned)BT), blk, 0, stream>>>(y, gamma2, beta2, h2);

    // mid = relu(h2 @ W1 + b1)
    gemm_nt<64, 128, bf16, float, true><<<dim3(8, 128, 1), blk, 0, stream>>>(
        h2, wt1, mid, b1, nullptr,
        (int)BT, Dn, Dn, Dn, Dn, Dn, 0, 0, 0, 0, 0);

    // out = mid @ W2 + b2 + y (fp32 out, bf16 residual)
    gemm_nt<64, 128, float, bf16, false><<<dim3(8, 128, 1), blk, 0, stream>>>(
        mid, wt2, out, b2, y,
        (int)BT, Dn, Dn, Dn, Dn, Dn, 0, 0, 0, 0, 0);
}

// Round 5
// 387.842 us; speedup vs baseline: 1.1518x; 1.0926x over previous
//
#include <hip/hip_runtime.h>
#include <hip/hip_bf16.h>
#include <math.h>

using bf16 = __hip_bfloat16;

static constexpr int Bn = 4;
static constexpr int Tn = 2048;
static constexpr int Dn = 1024;

typedef __attribute__((ext_vector_type(8))) short bf16x8;
typedef __attribute__((ext_vector_type(4))) float f32x4;

__device__ __forceinline__ float ldf(float v) { return v; }
__device__ __forceinline__ float ldf(bf16 v) { return __bfloat162float(v); }
__device__ __forceinline__ bf16 f2b(float v) { return __float2bfloat16(v); }
__device__ __forceinline__ float b2f(short s) {
    return __uint_as_float(((unsigned)(unsigned short)s) << 16);
}
__device__ __forceinline__ short f2bs(float v) {
    bf16 t = __float2bfloat16(v);
    return *reinterpret_cast<short*>(&t);
}

template <typename T> __device__ __forceinline__ T from_float(float v);
template <> __device__ __forceinline__ float from_float<float>(float v) { return v; }
template <> __device__ __forceinline__ bf16 from_float<bf16>(float v) { return f2b(v); }

__device__ __forceinline__ void load4(const float* p, float* v) {
    const float4 t = *(const float4*)p;
    v[0] = t.x; v[1] = t.y; v[2] = t.z; v[3] = t.w;
}
__device__ __forceinline__ void load4(const bf16* p, float* v) {
    const short4 t = *(const short4*)p;
    v[0] = b2f(t.x); v[1] = b2f(t.y); v[2] = b2f(t.z); v[3] = b2f(t.w);
}

// async global->LDS, 16B per lane; LDS dest wave-uniform base, HW scatters +lane*16.
__device__ __forceinline__ void async_copy16(const bf16* g, bf16* l) {
    __builtin_amdgcn_global_load_lds(
        (const __attribute__((address_space(1))) void*)g,
        (__attribute__((address_space(3))) void*)l,
        16, 0, 0);
}

// ---------------------------------------------------------------------------
// Generic NT GEMM: C[m,n] = sum_k A[m,k]*B[n,k], bf16 inputs, explicit ld's.
// BK=64 realized as TWO BK=32 sub-stages (row stride stays 32 elems = 64 B --
// the m97-validated LDS geometry; a real 128 B row stride would be 16-way
// bank-conflicted and padding is impossible with global_load_lds).
// One barrier pair per 64 K-elements => 2x MFMA per barrier vs round 4.
// BM=128: waves 2x2 (wave tile 64x64). BM=64: waves 1x4 (wave tile 64x32).
// mode 0: full; 1: skip blocks fully above diagonal; 2: K truncated at bm*BM+BM.
// ---------------------------------------------------------------------------
template <int BM, int BN, int MINW, typename OutT, typename ResT, bool RELU>
__global__ __launch_bounds__(256, MINW) void gemm_nt(
    const bf16* __restrict__ A, const bf16* __restrict__ Bm,
    OutT* __restrict__ C, const float* __restrict__ bias,
    const ResT* __restrict__ res,
    int M, int N, int K, int lda, int ldb, int ldc,
    long sA, long sB, long sC, long sR, int mode)
{
    const int bm = blockIdx.y, bn = blockIdx.x, bz = blockIdx.z;
    if (mode == 1 && bn * BN > bm * BM + (BM - 1)) return;
    const int kend = bm * BM + BM;
    const int kmax = (mode == 2) ? (kend < K ? kend : K) : K;

    const bf16* Ab = A + (size_t)bz * sA;
    const bf16* Bb = Bm + (size_t)bz * sB;

    constexpr int WROWS = BM / 64;          // 2 or 1
    constexpr int WCOLS = 4 / WROWS;        // 2 or 4
    constexpr int TM = 64;
    constexpr int TN = BN / WCOLS;          // 64 or 32
    constexpr int MT = TM / 16;             // 4
    constexpr int NT = TN / 16;             // 4 or 2
    constexpr int nA = BM / 16;             // 1KB chunks per 32-col half
    constexpr int nB = BN / 16;

    // two halves per buffer: half h occupies [h*BM*32, ...)
    __shared__ __align__(16) bf16 As[2 * BM * 32];
    __shared__ __align__(16) bf16 Bs[2 * BN * 32];

    const int tid = threadIdx.x;
    const int wave = tid >> 6;
    const int lane = tid & 63;
    const int wm = wave / WCOLS;
    const int wn = wave % WCOLS;

    f32x4 acc[MT][NT] = {};

    // staging: chunk c covers rows [c*16, c*16+16) x 32 cols = 1KB
    const int lr = lane >> 2;
    const int lc = (lane & 3) * 8;
    const bf16* gAc[nA / 4]; bf16* lAc[nA / 4];
    const bf16* gBc[nB / 4]; bf16* lBc[nB / 4];
#pragma unroll
    for (int i = 0; i < nA / 4; ++i) {
        const int c = wave + 4 * i;
        gAc[i] = Ab + (size_t)(bm * BM + c * 16 + lr) * lda + lc;
        lAc[i] = &As[c * 512];
    }
#pragma unroll
    for (int i = 0; i < nB / 4; ++i) {
        const int c = wave + 4 * i;
        gBc[i] = Bb + (size_t)(bn * BN + c * 16 + lr) * ldb + lc;
        lBc[i] = &Bs[c * 512];
    }

    const int arow = lane & 15;
    const int kq = (lane >> 4) * 8;

    for (int k0 = 0; k0 < kmax; k0 += 64) {
#pragma unroll
        for (int hh = 0; hh < 2; ++hh) {
#pragma unroll
            for (int i = 0; i < nA / 4; ++i)
                async_copy16(gAc[i] + k0 + 32 * hh, lAc[i] + hh * (BM * 32));
#pragma unroll
            for (int i = 0; i < nB / 4; ++i)
                async_copy16(gBc[i] + k0 + 32 * hh, lBc[i] + hh * (BN * 32));
        }
        __syncthreads();

#pragma unroll
        for (int hh = 0; hh < 2; ++hh) {
            const bf16* Ah = As + hh * (BM * 32);
            const bf16* Bh = Bs + hh * (BN * 32);
            bf16x8 af[MT], bfm[NT];
#pragma unroll
            for (int t = 0; t < MT; ++t)
                af[t] = *(const bf16x8*)&Ah[(wm * TM + t * 16 + arow) * 32 + kq];
#pragma unroll
            for (int t = 0; t < NT; ++t)
                bfm[t] = *(const bf16x8*)&Bh[(wn * TN + t * 16 + arow) * 32 + kq];
#pragma unroll
            for (int mt = 0; mt < MT; ++mt)
#pragma unroll
                for (int nt = 0; nt < NT; ++nt)
                    acc[mt][nt] = __builtin_amdgcn_mfma_f32_16x16x32_bf16(
                        af[mt], bfm[nt], acc[mt][nt], 0, 0, 0);
        }
        __syncthreads();
    }

    // epilogue: C/D layout col = lane&15, row = (lane>>4)*4 + reg
    OutT* Cb = C + (size_t)bz * sC;
    const ResT* Rb = res ? (res + (size_t)bz * sR) : nullptr;
    const int rowBase = bm * BM + wm * TM;
    const int colBase = bn * BN + wn * TN;
    const int qrow = (lane >> 4) * 4;
    const int ccol = lane & 15;

#pragma unroll
    for (int mt = 0; mt < MT; ++mt) {
#pragma unroll
        for (int nt = 0; nt < NT; ++nt) {
            const int cc = colBase + nt * 16 + ccol;
            const float bv = bias ? bias[cc] : 0.0f;
#pragma unroll
            for (int r = 0; r < 4; ++r) {
                const int rr = rowBase + mt * 16 + qrow + r;
                float v = acc[mt][nt][r] + bv;
                if (RELU) v = fmaxf(v, 0.0f);
                if (Rb) v += ldf(Rb[(size_t)rr * ldc + cc]);
                Cb[(size_t)rr * ldc + cc] = from_float<OutT>(v);
            }
        }
    }
}

// ---------------------------------------------------------------------------
// LayerNorm (faithfully buggy): out = (x - mean/sqrt(var_unbiased))*gamma + beta
// ---------------------------------------------------------------------------
template <typename InT>
__global__ __launch_bounds__(256) void ln_kernel(
    const InT* __restrict__ x, const float* __restrict__ gamma,
    const float* __restrict__ beta, bf16* __restrict__ out)
{
    const int row = blockIdx.x;
    const int tid = threadIdx.x;
    const int j = tid * 4;
    const InT* xr = x + (size_t)row * Dn;

    float v[4];
    load4(xr + j, v);
    float s = v[0] + v[1] + v[2] + v[3];
    float sq = v[0] * v[0] + v[1] * v[1] + v[2] * v[2] + v[3] * v[3];
#pragma unroll
    for (int o = 32; o > 0; o >>= 1) {
        s += __shfl_down(s, o);
        sq += __shfl_down(sq, o);
    }
    __shared__ float red[2][4];
    const int lane = tid & 63, w = tid >> 6;
    if (lane == 0) { red[0][w] = s; red[1][w] = sq; }
    __syncthreads();
    s  = red[0][0] + red[0][1] + red[0][2] + red[0][3];
    sq = red[1][0] + red[1][1] + red[1][2] + red[1][3];
    const float mean = s / (float)Dn;
    const float var = (sq - s * s / (float)Dn) / (float)(Dn - 1);
    const float coef = mean * rsqrtf(var);

    const float4 g = *(const float4*)(gamma + j);
    const float4 be = *(const float4*)(beta + j);
    short4 o;
    o.x = f2bs((v[0] - coef) * g.x + be.x);
    o.y = f2bs((v[1] - coef) * g.y + be.y);
    o.z = f2bs((v[2] - coef) * g.z + be.z);
    o.w = f2bs((v[3] - coef) * g.w + be.w);
    *(short4*)(out + (size_t)row * Dn + j) = o;
}

// ---------------------------------------------------------------------------
// Causal softmax, bf16 in / bf16 out. One block per row; thread owns 8 elems.
// ---------------------------------------------------------------------------
__global__ __launch_bounds__(256) void softmax_kernel(
    const bf16* __restrict__ S, bf16* __restrict__ P)
{
    const int r = blockIdx.x;
    const int b = r >> 11, i = r & (Tn - 1);
    const bf16* srow = S + ((size_t)b * Tn + i) * Tn;
    bf16* prow = P + ((size_t)b * Tn + i) * Tn;
    const int L = i + 1;
    const float scale = 0.03125f;  // 1/sqrt(1024)
    const int tid = threadIdx.x;
    const int j0 = tid * 8;
    const int lane = tid & 63, w = tid >> 6;

    const bf16x8 sv = *(const bf16x8*)(srow + j0);
    float v[8];
#pragma unroll
    for (int e = 0; e < 8; ++e)
        v[e] = (j0 + e < L) ? b2f(sv[e]) * scale : -INFINITY;

    float mx = v[0];
#pragma unroll
    for (int e = 1; e < 8; ++e) mx = fmaxf(mx, v[e]);
#pragma unroll
    for (int o = 32; o > 0; o >>= 1) mx = fmaxf(mx, __shfl_down(mx, o));
    __shared__ float rmx[4], rsum[4];
    if (lane == 0) rmx[w] = mx;
    __syncthreads();
    mx = fmaxf(fmaxf(rmx[0], rmx[1]), fmaxf(rmx[2], rmx[3]));

    float p[8], sum = 0.f;
#pragma unroll
    for (int e = 0; e < 8; ++e) { p[e] = __expf(v[e] - mx); sum += p[e]; }
#pragma unroll
    for (int o = 32; o > 0; o >>= 1) sum += __shfl_down(sum, o);
    if (lane == 0) rsum[w] = sum;
    __syncthreads();
    sum = rsum[0] + rsum[1] + rsum[2] + rsum[3];
    const float inv = 1.0f / sum;

    bf16x8 pv;
#pragma unroll
    for (int e = 0; e < 8; ++e) pv[e] = f2bs(p[e] * inv);
    *(bf16x8*)(prow + j0) = pv;
}

// ---------------------------------------------------------------------------
// Transpose + convert to bf16: out[c*ldo + r] = bf16(in[r*ldi + c]); batched z.
// ---------------------------------------------------------------------------
template <typename InT>
__global__ __launch_bounds__(256) void transpose_kernel(
    const InT* __restrict__ in, bf16* __restrict__ out,
    int ldi, int ldo, long inStride, long outStride)
{
    __shared__ bf16 tile[32][33];
    const int z = blockIdx.z;
    const InT* src = in + (size_t)z * inStride;
    bf16* dst = out + (size_t)z * outStride;
    const int c0 = blockIdx.x * 32, r0 = blockIdx.y * 32;
    const int tx = threadIdx.x & 31;
    const int ty = threadIdx.x >> 5;
#pragma unroll
    for (int dy = 0; dy < 32; dy += 8)
        tile[ty + dy][tx] = f2b(ldf(src[(size_t)(r0 + ty + dy) * ldi + (c0 + tx)]));
    __syncthreads();
#pragma unroll
    for (int dy = 0; dy < 32; dy += 8)
        dst[(size_t)(c0 + ty + dy) * ldo + (r0 + tx)] = tile[tx][ty + dy];
}

extern "C" void kernel_launch(void* const* d_in, const int* in_sizes, int n_in,
                              void* d_out, int out_size, void* d_ws, size_t ws_size,
                              hipStream_t stream) {
    const float* x      = (const float*)d_in[0];
    const float* gamma1 = (const float*)d_in[1];
    const float* beta1  = (const float*)d_in[2];
    const float* w_q    = (const float*)d_in[3];
    const float* w_k    = (const float*)d_in[4];
    const float* w_v    = (const float*)d_in[5];
    const float* gamma2 = (const float*)d_in[6];
    const float* beta2  = (const float*)d_in[7];
    const float* W1     = (const float*)d_in[8];
    const float* b1     = (const float*)d_in[9];
    const float* W2     = (const float*)d_in[10];
    const float* b2     = (const float*)d_in[11];
    float* out = (float*)d_out;   // fp32 output buffer (compared in bf16 space)

    char* ws = (char*)d_ws;
    size_t off = 0;
    auto alloc = [&](size_t bytes) {
        char* p = ws + off;
        off += (bytes + 255) & ~(size_t)255;
        return p;
    };
    const size_t BT = (size_t)Bn * Tn;
    bf16* h     = (bf16*)alloc(BT * Dn * 2);               // 16 MB; reused as h2
    bf16* qkv   = (bf16*)alloc(BT * 3 * Dn * 2);           // 48 MB [8192,3072]
    bf16* vt    = (bf16*)alloc(BT * Dn * 2);               // 16 MB [4][1024,2048]
    bf16* wqkvt = (bf16*)alloc((size_t)3 * Dn * Dn * 2);   //  6 MB [3072,1024]
    bf16* wt1   = (bf16*)alloc((size_t)Dn * Dn * 2);       //  2 MB
    bf16* wt2   = (bf16*)alloc((size_t)Dn * Dn * 2);       //  2 MB
    bf16* S     = (bf16*)alloc((size_t)Bn * Tn * Tn * 2);  // 32 MB
    bf16* P     = (bf16*)alloc((size_t)Bn * Tn * Tn * 2);  // 32 MB
    bf16* y     = S;            // overlay: S dead after softmax
    bf16* h2    = h;            // h dead after QKV
    bf16* mid   = qkv;          // qkv dead after PV

    const dim3 blk(256);
    const long TD   = (long)Tn * Dn;
    const long TT   = (long)Tn * Tn;
    const long TD3  = (long)Tn * 3 * Dn;

    // weight transposes + fp32->bf16: W[k,d] -> WT[d,k]; QKV concatenated.
    transpose_kernel<float><<<dim3(32, 32, 1), blk, 0, stream>>>(w_q, wqkvt,                Dn, Dn, 0, 0);
    transpose_kernel<float><<<dim3(32, 32, 1), blk, 0, stream>>>(w_k, wqkvt + 1024 * 1024,  Dn, Dn, 0, 0);
    transpose_kernel<float><<<dim3(32, 32, 1), blk, 0, stream>>>(w_v, wqkvt + 2048 * 1024,  Dn, Dn, 0, 0);
    transpose_kernel<float><<<dim3(32, 32, 1), blk, 0, stream>>>(W1, wt1, Dn, Dn, 0, 0);
    transpose_kernel<float><<<dim3(32, 32, 1), blk, 0, stream>>>(W2, wt2, Dn, Dn, 0, 0);

    // LN1: x -> h (bf16)
    ln_kernel<float><<<dim3((unsigned)BT), blk, 0, stream>>>(x, gamma1, beta1, h);

    // merged QKV: [8192,1024] @ [1024,3072] -> qkv [8192,3072]
    gemm_nt<128, 128, 3, bf16, float, false><<<dim3(24, 64, 1), blk, 0, stream>>>(
        h, wqkvt, qkv, nullptr, nullptr,
        (int)BT, 3 * Dn, Dn, Dn, Dn, 3 * Dn, 0, 0, 0, 0, 0);

    // V^T per batch: v = qkv cols [2048,3072) -> vt [1024,2048]
    transpose_kernel<bf16><<<dim3(32, 64, Bn), blk, 0, stream>>>(
        qkv + 2048, vt, 3 * Dn, Tn, TD3, TD);

    // scores = q @ k^T (batched, causal block-skip), bf16 out
    gemm_nt<128, 128, 3, bf16, float, false><<<dim3(16, 16, Bn), blk, 0, stream>>>(
        qkv, qkv + 1024, S, nullptr, nullptr,
        Tn, Tn, Dn, 3 * Dn, 3 * Dn, Tn, TD3, TD3, TT, 0, 1);

    // softmax -> P (bf16, zeros above diagonal)
    softmax_kernel<<<dim3((unsigned)BT), blk, 0, stream>>>(S, P);

    // y = P @ V + x (batched, K truncated), bf16 out, res = x (fp32)
    gemm_nt<64, 128, 4, bf16, float, false><<<dim3(8, 32, Bn), blk, 0, stream>>>(
        P, vt, y, nullptr, x,
        Tn, Dn, Tn, Tn, Tn, Dn, TT, TD, TD, TD, 2);

    // LN2: y (bf16) -> h2 (bf16)
    ln_kernel<bf16><<<dim3((unsigned)BT), blk, 0, stream>>>(y, gamma2, beta2, h2);

    // mid = relu(h2 @ W1 + b1)
    gemm_nt<128, 128, 3, bf16, float, true><<<dim3(8, 64, 1), blk, 0, stream>>>(
        h2, wt1, mid, b1, nullptr,
        (int)BT, Dn, Dn, Dn, Dn, Dn, 0, 0, 0, 0, 0);

    // out = mid @ W2 + b2 + y (fp32 out, bf16 residual)
    gemm_nt<128, 128, 3, float, bf16, false><<<dim3(8, 64, 1), blk, 0, stream>>>(
        mid, wt2, out, b2, y,
        (int)BT, Dn, Dn, Dn, Dn, Dn, 0, 0, 0, 0, 0);
}

// Round 6
// 363.570 us; speedup vs baseline: 1.2287x; 1.0668x over previous
//
#include <hip/hip_runtime.h>
#include <hip/hip_bf16.h>
#include <math.h>

using bf16 = __hip_bfloat16;

static constexpr int Bn = 4;
static constexpr int Tn = 2048;
static constexpr int Dn = 1024;

typedef __attribute__((ext_vector_type(8))) short bf16x8;
typedef __attribute__((ext_vector_type(4))) float f32x4;

__device__ __forceinline__ float ldf(float v) { return v; }
__device__ __forceinline__ float ldf(bf16 v) { return __bfloat162float(v); }
__device__ __forceinline__ bf16 f2b(float v) { return __float2bfloat16(v); }
__device__ __forceinline__ float b2f(short s) {
    return __uint_as_float(((unsigned)(unsigned short)s) << 16);
}
__device__ __forceinline__ short f2bs(float v) {
    bf16 t = __float2bfloat16(v);
    return *reinterpret_cast<short*>(&t);
}

template <typename T> __device__ __forceinline__ T from_float(float v);
template <> __device__ __forceinline__ float from_float<float>(float v) { return v; }
template <> __device__ __forceinline__ bf16 from_float<bf16>(float v) { return f2b(v); }

__device__ __forceinline__ void load4(const float* p, float* v) {
    const float4 t = *(const float4*)p;
    v[0] = t.x; v[1] = t.y; v[2] = t.z; v[3] = t.w;
}
__device__ __forceinline__ void load4(const bf16* p, float* v) {
    const short4 t = *(const short4*)p;
    v[0] = b2f(t.x); v[1] = b2f(t.y); v[2] = b2f(t.z); v[3] = b2f(t.w);
}

// async global->LDS, 16B per lane; LDS dest wave-uniform base, HW scatters +lane*16.
__device__ __forceinline__ void async_copy16(const bf16* g, bf16* l) {
    __builtin_amdgcn_global_load_lds(
        (const __attribute__((address_space(1))) void*)g,
        (__attribute__((address_space(3))) void*)l,
        16, 0, 0);
}

// ---------------------------------------------------------------------------
// Generic NT GEMM: C[m,n] = sum_k A[m,k]*B[n,k], bf16 inputs, explicit ld's.
// BK=64 as two BK=32 sub-stages (64 B LDS row stride, m97-validated geometry).
// 128x128 tile, 4 waves 2x2, wave tile 64x64 -> 32 MFMA per barrier pair.
// mode 0: full; 1: skip blocks fully above diagonal; 2: K truncated at bm*BM+BM.
// VSPLIT (QKV): blocks with col>=2048 write acc TRANSPOSED into vtp
// (vt[b][d][t], d = col-2048), fusing the V^T kernel into the epilogue.
// ---------------------------------------------------------------------------
template <int BM, int BN, int MINW, typename OutT, typename ResT, bool RELU, bool VSPLIT>
__global__ __launch_bounds__(256, MINW) void gemm_nt(
    const bf16* __restrict__ A, const bf16* __restrict__ Bm,
    OutT* __restrict__ C, const float* __restrict__ bias,
    const ResT* __restrict__ res, bf16* __restrict__ vtp,
    int M, int N, int K, int lda, int ldb, int ldc,
    long sA, long sB, long sC, long sR, int mode)
{
    const int bm = blockIdx.y, bn = blockIdx.x, bz = blockIdx.z;
    if (mode == 1 && bn * BN > bm * BM + (BM - 1)) return;
    const int kend = bm * BM + BM;
    const int kmax = (mode == 2) ? (kend < K ? kend : K) : K;

    const bf16* Ab = A + (size_t)bz * sA;
    const bf16* Bb = Bm + (size_t)bz * sB;

    constexpr int WROWS = BM / 64;
    constexpr int WCOLS = 4 / WROWS;
    constexpr int TM = 64;
    constexpr int TN = BN / WCOLS;
    constexpr int MT = TM / 16;
    constexpr int NT = TN / 16;
    constexpr int nA = BM / 16;
    constexpr int nB = BN / 16;

    __shared__ __align__(16) bf16 As[2 * BM * 32];
    __shared__ __align__(16) bf16 Bs[2 * BN * 32];

    const int tid = threadIdx.x;
    const int wave = tid >> 6;
    const int lane = tid & 63;
    const int wm = wave / WCOLS;
    const int wn = wave % WCOLS;

    f32x4 acc[MT][NT] = {};

    const int lr = lane >> 2;
    const int lc = (lane & 3) * 8;
    const bf16* gAc[nA / 4]; bf16* lAc[nA / 4];
    const bf16* gBc[nB / 4]; bf16* lBc[nB / 4];
#pragma unroll
    for (int i = 0; i < nA / 4; ++i) {
        const int c = wave + 4 * i;
        gAc[i] = Ab + (size_t)(bm * BM + c * 16 + lr) * lda + lc;
        lAc[i] = &As[c * 512];
    }
#pragma unroll
    for (int i = 0; i < nB / 4; ++i) {
        const int c = wave + 4 * i;
        gBc[i] = Bb + (size_t)(bn * BN + c * 16 + lr) * ldb + lc;
        lBc[i] = &Bs[c * 512];
    }

    const int arow = lane & 15;
    const int kq = (lane >> 4) * 8;

    for (int k0 = 0; k0 < kmax; k0 += 64) {
#pragma unroll
        for (int hh = 0; hh < 2; ++hh) {
#pragma unroll
            for (int i = 0; i < nA / 4; ++i)
                async_copy16(gAc[i] + k0 + 32 * hh, lAc[i] + hh * (BM * 32));
#pragma unroll
            for (int i = 0; i < nB / 4; ++i)
                async_copy16(gBc[i] + k0 + 32 * hh, lBc[i] + hh * (BN * 32));
        }
        __syncthreads();

#pragma unroll
        for (int hh = 0; hh < 2; ++hh) {
            const bf16* Ah = As + hh * (BM * 32);
            const bf16* Bh = Bs + hh * (BN * 32);
            bf16x8 af[MT], bfm[NT];
#pragma unroll
            for (int t = 0; t < MT; ++t)
                af[t] = *(const bf16x8*)&Ah[(wm * TM + t * 16 + arow) * 32 + kq];
#pragma unroll
            for (int t = 0; t < NT; ++t)
                bfm[t] = *(const bf16x8*)&Bh[(wn * TN + t * 16 + arow) * 32 + kq];
#pragma unroll
            for (int mt = 0; mt < MT; ++mt)
#pragma unroll
                for (int nt = 0; nt < NT; ++nt)
                    acc[mt][nt] = __builtin_amdgcn_mfma_f32_16x16x32_bf16(
                        af[mt], bfm[nt], acc[mt][nt], 0, 0, 0);
        }
        __syncthreads();
    }

    // epilogue: C/D layout col = lane&15, row = (lane>>4)*4 + reg
    const int rowBase = bm * BM + wm * TM;
    const int colBase = bn * BN + wn * TN;
    const int qrow = (lane >> 4) * 4;
    const int ccol = lane & 15;

    if (VSPLIT && bn * BN >= 2048) {
        // V columns: write transposed into vt[b][d][t]; 4 consecutive t per lane.
#pragma unroll
        for (int mt = 0; mt < MT; ++mt) {
            const int t0 = rowBase + mt * 16 + qrow;    // flat row (b*Tn + t)
            const int b = t0 >> 11, t = t0 & (Tn - 1);
            bf16* vb = vtp + (size_t)b * Dn * Tn + t;
#pragma unroll
            for (int nt = 0; nt < NT; ++nt) {
                const int d = colBase + nt * 16 + ccol - 2048;
                short4 o;
                o.x = f2bs(acc[mt][nt][0]);
                o.y = f2bs(acc[mt][nt][1]);
                o.z = f2bs(acc[mt][nt][2]);
                o.w = f2bs(acc[mt][nt][3]);
                *(short4*)(vb + (size_t)d * Tn) = o;
            }
        }
        return;
    }

    OutT* Cb = C + (size_t)bz * sC;
    const ResT* Rb = res ? (res + (size_t)bz * sR) : nullptr;
#pragma unroll
    for (int mt = 0; mt < MT; ++mt) {
#pragma unroll
        for (int nt = 0; nt < NT; ++nt) {
            const int cc = colBase + nt * 16 + ccol;
            const float bv = bias ? bias[cc] : 0.0f;
#pragma unroll
            for (int r = 0; r < 4; ++r) {
                const int rr = rowBase + mt * 16 + qrow + r;
                float v = acc[mt][nt][r] + bv;
                if (RELU) v = fmaxf(v, 0.0f);
                if (Rb) v += ldf(Rb[(size_t)rr * ldc + cc]);
                Cb[(size_t)rr * ldc + cc] = from_float<OutT>(v);
            }
        }
    }
}

// ---------------------------------------------------------------------------
// LayerNorm (faithfully buggy): out = (x - mean/sqrt(var_unbiased))*gamma + beta
// ---------------------------------------------------------------------------
template <typename InT>
__global__ __launch_bounds__(256) void ln_kernel(
    const InT* __restrict__ x, const float* __restrict__ gamma,
    const float* __restrict__ beta, bf16* __restrict__ out)
{
    const int row = blockIdx.x;
    const int tid = threadIdx.x;
    const int j = tid * 4;
    const InT* xr = x + (size_t)row * Dn;

    float v[4];
    load4(xr + j, v);
    float s = v[0] + v[1] + v[2] + v[3];
    float sq = v[0] * v[0] + v[1] * v[1] + v[2] * v[2] + v[3] * v[3];
#pragma unroll
    for (int o = 32; o > 0; o >>= 1) {
        s += __shfl_down(s, o);
        sq += __shfl_down(sq, o);
    }
    __shared__ float red[2][4];
    const int lane = tid & 63, w = tid >> 6;
    if (lane == 0) { red[0][w] = s; red[1][w] = sq; }
    __syncthreads();
    s  = red[0][0] + red[0][1] + red[0][2] + red[0][3];
    sq = red[1][0] + red[1][1] + red[1][2] + red[1][3];
    const float mean = s / (float)Dn;
    const float var = (sq - s * s / (float)Dn) / (float)(Dn - 1);
    const float coef = mean * rsqrtf(var);

    const float4 g = *(const float4*)(gamma + j);
    const float4 be = *(const float4*)(beta + j);
    short4 o;
    o.x = f2bs((v[0] - coef) * g.x + be.x);
    o.y = f2bs((v[1] - coef) * g.y + be.y);
    o.z = f2bs((v[2] - coef) * g.z + be.z);
    o.w = f2bs((v[3] - coef) * g.w + be.w);
    *(short4*)(out + (size_t)row * Dn + j) = o;
}

// ---------------------------------------------------------------------------
// Causal softmax, bf16 in / bf16 out. One block per row; thread owns 8 elems.
// Loads skipped beyond the causal boundary (those probs are written as 0).
// ---------------------------------------------------------------------------
__global__ __launch_bounds__(256) void softmax_kernel(
    const bf16* __restrict__ S, bf16* __restrict__ P)
{
    const int r = blockIdx.x;
    const int b = r >> 11, i = r & (Tn - 1);
    const bf16* srow = S + ((size_t)b * Tn + i) * Tn;
    bf16* prow = P + ((size_t)b * Tn + i) * Tn;
    const int L = i + 1;
    const float scale = 0.03125f;  // 1/sqrt(1024)
    const int tid = threadIdx.x;
    const int j0 = tid * 8;
    const int lane = tid & 63, w = tid >> 6;

    float v[8];
    if (j0 < L) {
        const bf16x8 sv = *(const bf16x8*)(srow + j0);
#pragma unroll
        for (int e = 0; e < 8; ++e)
            v[e] = (j0 + e < L) ? b2f(sv[e]) * scale : -INFINITY;
    } else {
#pragma unroll
        for (int e = 0; e < 8; ++e) v[e] = -INFINITY;
    }

    float mx = v[0];
#pragma unroll
    for (int e = 1; e < 8; ++e) mx = fmaxf(mx, v[e]);
#pragma unroll
    for (int o = 32; o > 0; o >>= 1) mx = fmaxf(mx, __shfl_down(mx, o));
    __shared__ float rmx[4], rsum[4];
    if (lane == 0) rmx[w] = mx;
    __syncthreads();
    mx = fmaxf(fmaxf(rmx[0], rmx[1]), fmaxf(rmx[2], rmx[3]));

    float p[8], sum = 0.f;
#pragma unroll
    for (int e = 0; e < 8; ++e) { p[e] = __expf(v[e] - mx); sum += p[e]; }
#pragma unroll
    for (int o = 32; o > 0; o >>= 1) sum += __shfl_down(sum, o);
    if (lane == 0) rsum[w] = sum;
    __syncthreads();
    sum = rsum[0] + rsum[1] + rsum[2] + rsum[3];
    const float inv = 1.0f / sum;

    bf16x8 pv;
#pragma unroll
    for (int e = 0; e < 8; ++e) pv[e] = f2bs(p[e] * inv);
    *(bf16x8*)(prow + j0) = pv;
}

// ---------------------------------------------------------------------------
// Batched weight transpose (fp32 -> bf16): 5 independent 1024x1024 matrices.
// dst[z][d][k] = bf16(src_z[k][d]); z = blockIdx.z.
// ---------------------------------------------------------------------------
struct WPtrs { const float* p[5]; };

__global__ __launch_bounds__(256) void wtrans_kernel(WPtrs wp, bf16* __restrict__ dst)
{
    __shared__ bf16 tile[32][33];
    const int z = blockIdx.z;
    const float* src = wp.p[z];
    bf16* d = dst + (size_t)z * Dn * Dn;
    const int c0 = blockIdx.x * 32, r0 = blockIdx.y * 32;
    const int tx = threadIdx.x & 31;
    const int ty = threadIdx.x >> 5;
#pragma unroll
    for (int dy = 0; dy < 32; dy += 8)
        tile[ty + dy][tx] = f2b(src[(size_t)(r0 + ty + dy) * Dn + (c0 + tx)]);
    __syncthreads();
#pragma unroll
    for (int dy = 0; dy < 32; dy += 8)
        d[(size_t)(c0 + ty + dy) * Dn + (r0 + tx)] = tile[tx][ty + dy];
}

extern "C" void kernel_launch(void* const* d_in, const int* in_sizes, int n_in,
                              void* d_out, int out_size, void* d_ws, size_t ws_size,
                              hipStream_t stream) {
    const float* x      = (const float*)d_in[0];
    const float* gamma1 = (const float*)d_in[1];
    const float* beta1  = (const float*)d_in[2];
    const float* w_q    = (const float*)d_in[3];
    const float* w_k    = (const float*)d_in[4];
    const float* w_v    = (const float*)d_in[5];
    const float* gamma2 = (const float*)d_in[6];
    const float* beta2  = (const float*)d_in[7];
    const float* W1     = (const float*)d_in[8];
    const float* b1     = (const float*)d_in[9];
    const float* W2     = (const float*)d_in[10];
    const float* b2     = (const float*)d_in[11];
    float* out = (float*)d_out;   // fp32 output buffer (compared in bf16 space)

    char* ws = (char*)d_ws;
    size_t off = 0;
    auto alloc = [&](size_t bytes) {
        char* p = ws + off;
        off += (bytes + 255) & ~(size_t)255;
        return p;
    };
    const size_t BT = (size_t)Bn * Tn;
    bf16* h    = (bf16*)alloc(BT * Dn * 2);               // 16 MB; reused as h2
    bf16* qk   = (bf16*)alloc(BT * 2 * Dn * 2);           // 32 MB [8192,2048] (q|k)
    bf16* vt   = (bf16*)alloc(BT * Dn * 2);               // 16 MB [4][1024,2048]
    bf16* wbuf = (bf16*)alloc((size_t)5 * Dn * Dn * 2);   // 10 MB (wq|wk|wv|w1|w2)^T
    bf16* S    = (bf16*)alloc((size_t)Bn * Tn * Tn * 2);  // 32 MB
    bf16* P    = (bf16*)alloc((size_t)Bn * Tn * Tn * 2);  // 32 MB
    bf16* y    = S;            // overlay: S dead after softmax
    bf16* h2   = h;            // h dead after QKV
    bf16* mid  = qk;           // qk dead after scores

    const dim3 blk(256);
    const long TD  = (long)Tn * Dn;
    const long TT  = (long)Tn * Tn;
    const long TD2 = (long)Tn * 2 * Dn;

    // all 5 weight transposes in one dispatch
    WPtrs wp; wp.p[0] = w_q; wp.p[1] = w_k; wp.p[2] = w_v; wp.p[3] = W1; wp.p[4] = W2;
    wtrans_kernel<<<dim3(32, 32, 5), blk, 0, stream>>>(wp, wbuf);

    // LN1: x -> h (bf16)
    ln_kernel<float><<<dim3((unsigned)BT), blk, 0, stream>>>(x, gamma1, beta1, h);

    // merged QKV: [8192,1024] @ [1024,3072]; q,k -> qk (ldc=2048), v -> vt (transposed)
    gemm_nt<128, 128, 4, bf16, float, false, true><<<dim3(24, 64, 1), blk, 0, stream>>>(
        h, wbuf, qk, nullptr, nullptr, vt,
        (int)BT, 3 * Dn, Dn, Dn, Dn, 2 * Dn, 0, 0, 0, 0, 0);

    // scores = q @ k^T (batched, causal block-skip), bf16 out
    gemm_nt<128, 128, 4, bf16, float, false, false><<<dim3(16, 16, Bn), blk, 0, stream>>>(
        qk, qk + 1024, S, nullptr, nullptr, nullptr,
        Tn, Tn, Dn, 2 * Dn, 2 * Dn, Tn, TD2, TD2, TT, 0, 1);

    // softmax -> P (bf16, zeros above diagonal)
    softmax_kernel<<<dim3((unsigned)BT), blk, 0, stream>>>(S, P);

    // y = P @ V + x (batched, K truncated), bf16 out, res = x (fp32)
    gemm_nt<128, 128, 4, bf16, float, false, false><<<dim3(8, 16, Bn), blk, 0, stream>>>(
        P, vt, y, nullptr, x, nullptr,
        Tn, Dn, Tn, Tn, Tn, Dn, TT, TD, TD, TD, 2);

    // LN2: y (bf16) -> h2 (bf16)
    ln_kernel<bf16><<<dim3((unsigned)BT), blk, 0, stream>>>(y, gamma2, beta2, h2);

    // mid = relu(h2 @ W1 + b1)
    gemm_nt<128, 128, 4, bf16, float, true, false><<<dim3(8, 64, 1), blk, 0, stream>>>(
        h2, wbuf + (size_t)3 * Dn * Dn, mid, b1, nullptr, nullptr,
        (int)BT, Dn, Dn, Dn, Dn, Dn, 0, 0, 0, 0, 0);

    // out = mid @ W2 + b2 + y (fp32 out, bf16 residual)
    gemm_nt<128, 128, 4, float, bf16, false, false><<<dim3(8, 64, 1), blk, 0, stream>>>(
        mid, wbuf + (size_t)4 * Dn * Dn, out, b2, y, nullptr,
        (int)BT, Dn, Dn, Dn, Dn, Dn, 0, 0, 0, 0, 0);
}

// Round 7
// 363.493 us; speedup vs baseline: 1.2289x; 1.0002x over previous
//
#include <hip/hip_runtime.h>
#include <hip/hip_bf16.h>
#include <math.h>

using bf16 = __hip_bfloat16;

static constexpr int Bn = 4;
static constexpr int Tn = 2048;
static constexpr int Dn = 1024;

typedef __attribute__((ext_vector_type(8))) short bf16x8;
typedef __attribute__((ext_vector_type(4))) float f32x4;

__device__ __forceinline__ float ldf(float v) { return v; }
__device__ __forceinline__ float ldf(bf16 v) { return __bfloat162float(v); }
__device__ __forceinline__ bf16 f2b(float v) { return __float2bfloat16(v); }
__device__ __forceinline__ float b2f(short s) {
    return __uint_as_float(((unsigned)(unsigned short)s) << 16);
}
__device__ __forceinline__ short f2bs(float v) {
    bf16 t = __float2bfloat16(v);
    return *reinterpret_cast<short*>(&t);
}

template <typename T> __device__ __forceinline__ T from_float(float v);
template <> __device__ __forceinline__ float from_float<float>(float v) { return v; }
template <> __device__ __forceinline__ bf16 from_float<bf16>(float v) { return f2b(v); }

__device__ __forceinline__ void load4(const float* p, float* v) {
    const float4 t = *(const float4*)p;
    v[0] = t.x; v[1] = t.y; v[2] = t.z; v[3] = t.w;
}
__device__ __forceinline__ void load4(const bf16* p, float* v) {
    const short4 t = *(const short4*)p;
    v[0] = b2f(t.x); v[1] = b2f(t.y); v[2] = b2f(t.z); v[3] = b2f(t.w);
}

// async global->LDS, 16B per lane; LDS dest wave-uniform base, HW scatters +lane*16.
__device__ __forceinline__ void async_copy16(const bf16* g, bf16* l) {
    __builtin_amdgcn_global_load_lds(
        (const __attribute__((address_space(1))) void*)g,
        (__attribute__((address_space(3))) void*)l,
        16, 0, 0);
}

// ---------------------------------------------------------------------------
// Generic NT GEMM: C[m,n] = sum_k A[m,k]*B[n,k], bf16 inputs, explicit ld's.
// BK=64 as two BK=32 sub-stages (64 B LDS row stride, m97-validated geometry).
// 128x128 tile, 4 waves 2x2, wave tile 64x64 -> 32 MFMA per barrier pair.
// mode 0: full; 1: skip blocks fully above diagonal; 2: K truncated at bm*BM+BM.
// EPI epilogue variants:
//  0: plain  (+bias, optional RELU, +res)
//  1: QKV    (cols<2048 -> plain C write ldc=2048; cols>=2048 -> V^T via LDS
//             transpose into vtp, coalesced 128B runs)
//  2: scores (write bf16(exp(acc*scale)) with causal mask col>row -> 0)
//  3: PV     (self-computed softmax row sums from A fragments; epilogue
//             scales acc by 1/rowsum, then +res)
// ---------------------------------------------------------------------------
template <int BM, int BN, int MINW, int EPI, typename OutT, typename ResT, bool RELU>
__global__ __launch_bounds__(256, MINW) void gemm_nt(
    const bf16* __restrict__ A, const bf16* __restrict__ Bm,
    OutT* __restrict__ C, const float* __restrict__ bias,
    const ResT* __restrict__ res, bf16* __restrict__ vtp,
    int M, int N, int K, int lda, int ldb, int ldc,
    long sA, long sB, long sC, long sR, int mode)
{
    const int bm = blockIdx.y, bn = blockIdx.x, bz = blockIdx.z;
    if (mode == 1 && bn * BN > bm * BM + (BM - 1)) return;
    const int kend = bm * BM + BM;
    const int kmax = (mode == 2) ? (kend < K ? kend : K) : K;

    const bf16* Ab = A + (size_t)bz * sA;
    const bf16* Bb = Bm + (size_t)bz * sB;

    constexpr int WROWS = BM / 64;
    constexpr int WCOLS = 4 / WROWS;
    constexpr int TM = 64;
    constexpr int TN = BN / WCOLS;
    constexpr int MT = TM / 16;
    constexpr int NT = TN / 16;
    constexpr int nA = BM / 16;
    constexpr int nB = BN / 16;
    constexpr int TSTR = 132;   // padded LDS stride for V^T transpose (EPI==1)
    constexpr int SME = (EPI == 1) ? (BM * TSTR) : (2 * (BM + BN) * 32);

    __shared__ __align__(16) bf16 smem[SME];
    __shared__ float rs[(EPI == 3) ? BM : 1];
    bf16* As = smem;
    bf16* Bs = smem + 2 * BM * 32;

    const int tid = threadIdx.x;
    const int wave = tid >> 6;
    const int lane = tid & 63;
    const int wm = wave / WCOLS;
    const int wn = wave % WCOLS;

    f32x4 acc[MT][NT] = {};
    float rsum[MT] = {};

    const int lr = lane >> 2;
    const int lc = (lane & 3) * 8;
    const bf16* gAc[nA / 4]; bf16* lAc[nA / 4];
    const bf16* gBc[nB / 4]; bf16* lBc[nB / 4];
#pragma unroll
    for (int i = 0; i < nA / 4; ++i) {
        const int c = wave + 4 * i;
        gAc[i] = Ab + (size_t)(bm * BM + c * 16 + lr) * lda + lc;
        lAc[i] = &As[c * 512];
    }
#pragma unroll
    for (int i = 0; i < nB / 4; ++i) {
        const int c = wave + 4 * i;
        gBc[i] = Bb + (size_t)(bn * BN + c * 16 + lr) * ldb + lc;
        lBc[i] = &Bs[c * 512];
    }

    const int arow = lane & 15;
    const int kq = (lane >> 4) * 8;

    for (int k0 = 0; k0 < kmax; k0 += 64) {
#pragma unroll
        for (int hh = 0; hh < 2; ++hh) {
#pragma unroll
            for (int i = 0; i < nA / 4; ++i)
                async_copy16(gAc[i] + k0 + 32 * hh, lAc[i] + hh * (BM * 32));
#pragma unroll
            for (int i = 0; i < nB / 4; ++i)
                async_copy16(gBc[i] + k0 + 32 * hh, lBc[i] + hh * (BN * 32));
        }
        __syncthreads();

#pragma unroll
        for (int hh = 0; hh < 2; ++hh) {
            const bf16* Ah = As + hh * (BM * 32);
            const bf16* Bh = Bs + hh * (BN * 32);
            bf16x8 af[MT], bfm[NT];
#pragma unroll
            for (int t = 0; t < MT; ++t)
                af[t] = *(const bf16x8*)&Ah[(wm * TM + t * 16 + arow) * 32 + kq];
#pragma unroll
            for (int t = 0; t < NT; ++t)
                bfm[t] = *(const bf16x8*)&Bh[(wn * TN + t * 16 + arow) * 32 + kq];
            if (EPI == 3 && wn == 0) {
                // softmax row-sum side-accumulation (A == masked exp scores)
#pragma unroll
                for (int t = 0; t < MT; ++t)
#pragma unroll
                    for (int e = 0; e < 8; ++e) rsum[t] += b2f(af[t][e]);
            }
#pragma unroll
            for (int mt = 0; mt < MT; ++mt)
#pragma unroll
                for (int nt = 0; nt < NT; ++nt)
                    acc[mt][nt] = __builtin_amdgcn_mfma_f32_16x16x32_bf16(
                        af[mt], bfm[nt], acc[mt][nt], 0, 0, 0);
        }
        __syncthreads();
    }

    const int rowBase = bm * BM + wm * TM;
    const int colBase = bn * BN + wn * TN;
    const int qrow = (lane >> 4) * 4;
    const int ccol = lane & 15;

    if (EPI == 3) {
        // finish row sums: reduce across the 4 k-offset lanes (lane>>4)
#pragma unroll
        for (int t = 0; t < MT; ++t) {
            float v = rsum[t];
            v += __shfl_xor(v, 16);
            v += __shfl_xor(v, 32);
            if (wn == 0 && lane < 16) rs[wm * TM + t * 16 + lane] = v;
        }
        __syncthreads();
    }

    if (EPI == 1 && bn * BN >= 2048) {
        // V columns: transpose via LDS, then coalesced writes to vt[b][d][t].
        bf16* tt = smem;   // safe: loop ended with __syncthreads()
#pragma unroll
        for (int mt = 0; mt < MT; ++mt) {
            const int tl = wm * TM + mt * 16 + qrow;   // local t, 4 consecutive
#pragma unroll
            for (int nt = 0; nt < NT; ++nt) {
                const int dl = wn * TN + nt * 16 + ccol;
                short4 o;
                o.x = f2bs(acc[mt][nt][0]);
                o.y = f2bs(acc[mt][nt][1]);
                o.z = f2bs(acc[mt][nt][2]);
                o.w = f2bs(acc[mt][nt][3]);
                *(short4*)&tt[dl * TSTR + tl] = o;
            }
        }
        __syncthreads();
        const int dl = tid >> 1;
        const int th = (tid & 1) * 64;
        const int dg = bn * BN - 2048 + dl;
        const int b = (bm * BM) >> 11;
        const int tin = (bm * BM) & (Tn - 1);
        bf16* dst = vtp + ((size_t)b * Dn + dg) * Tn + tin + th;
        const bf16* srcl = &tt[dl * TSTR + th];
#pragma unroll
        for (int i = 0; i < 16; ++i)
            ((short4*)dst)[i] = ((const short4*)srcl)[i];
        return;
    }

    if (EPI == 2) {
        // masked exp scores: S_exp = exp(acc*scale) if col<=row else 0
        OutT* Cb = C + (size_t)bz * sC;
        const float scale = 0.03125f;
#pragma unroll
        for (int mt = 0; mt < MT; ++mt) {
#pragma unroll
            for (int nt = 0; nt < NT; ++nt) {
                const int cc = colBase + nt * 16 + ccol;
#pragma unroll
                for (int r = 0; r < 4; ++r) {
                    const int rr = rowBase + mt * 16 + qrow + r;
                    const float e = (cc <= rr) ? __expf(acc[mt][nt][r] * scale) : 0.0f;
                    Cb[(size_t)rr * ldc + cc] = from_float<OutT>(e);
                }
            }
        }
        return;
    }

    OutT* Cb = C + (size_t)bz * sC;
    const ResT* Rb = res ? (res + (size_t)bz * sR) : nullptr;
#pragma unroll
    for (int mt = 0; mt < MT; ++mt) {
        float inv4[4];
        if (EPI == 3) {
#pragma unroll
            for (int r = 0; r < 4; ++r)
                inv4[r] = 1.0f / rs[wm * TM + mt * 16 + qrow + r];
        }
#pragma unroll
        for (int nt = 0; nt < NT; ++nt) {
            const int cc = colBase + nt * 16 + ccol;
            const float bv = bias ? bias[cc] : 0.0f;
#pragma unroll
            for (int r = 0; r < 4; ++r) {
                const int rr = rowBase + mt * 16 + qrow + r;
                float v = acc[mt][nt][r];
                if (EPI == 3) v *= inv4[r];
                v += bv;
                if (RELU) v = fmaxf(v, 0.0f);
                if (Rb) v += ldf(Rb[(size_t)rr * ldc + cc]);
                Cb[(size_t)rr * ldc + cc] = from_float<OutT>(v);
            }
        }
    }
}

// ---------------------------------------------------------------------------
// LayerNorm (faithfully buggy): out = (x - mean/sqrt(var_unbiased))*gamma + beta
// ---------------------------------------------------------------------------
template <typename InT>
__global__ __launch_bounds__(256) void ln_kernel(
    const InT* __restrict__ x, const float* __restrict__ gamma,
    const float* __restrict__ beta, bf16* __restrict__ out)
{
    const int row = blockIdx.x;
    const int tid = threadIdx.x;
    const int j = tid * 4;
    const InT* xr = x + (size_t)row * Dn;

    float v[4];
    load4(xr + j, v);
    float s = v[0] + v[1] + v[2] + v[3];
    float sq = v[0] * v[0] + v[1] * v[1] + v[2] * v[2] + v[3] * v[3];
#pragma unroll
    for (int o = 32; o > 0; o >>= 1) {
        s += __shfl_down(s, o);
        sq += __shfl_down(sq, o);
    }
    __shared__ float red[2][4];
    const int lane = tid & 63, w = tid >> 6;
    if (lane == 0) { red[0][w] = s; red[1][w] = sq; }
    __syncthreads();
    s  = red[0][0] + red[0][1] + red[0][2] + red[0][3];
    sq = red[1][0] + red[1][1] + red[1][2] + red[1][3];
    const float mean = s / (float)Dn;
    const float var = (sq - s * s / (float)Dn) / (float)(Dn - 1);
    const float coef = mean * rsqrtf(var);

    const float4 g = *(const float4*)(gamma + j);
    const float4 be = *(const float4*)(beta + j);
    short4 o;
    o.x = f2bs((v[0] - coef) * g.x + be.x);
    o.y = f2bs((v[1] - coef) * g.y + be.y);
    o.z = f2bs((v[2] - coef) * g.z + be.z);
    o.w = f2bs((v[3] - coef) * g.w + be.w);
    *(short4*)(out + (size_t)row * Dn + j) = o;
}

// ---------------------------------------------------------------------------
// Batched weight transpose (fp32 -> bf16): 5 independent 1024x1024 matrices.
// ---------------------------------------------------------------------------
struct WPtrs { const float* p[5]; };

__global__ __launch_bounds__(256) void wtrans_kernel(WPtrs wp, bf16* __restrict__ dst)
{
    __shared__ bf16 tile[32][33];
    const int z = blockIdx.z;
    const float* src = wp.p[z];
    bf16* d = dst + (size_t)z * Dn * Dn;
    const int c0 = blockIdx.x * 32, r0 = blockIdx.y * 32;
    const int tx = threadIdx.x & 31;
    const int ty = threadIdx.x >> 5;
#pragma unroll
    for (int dy = 0; dy < 32; dy += 8)
        tile[ty + dy][tx] = f2b(src[(size_t)(r0 + ty + dy) * Dn + (c0 + tx)]);
    __syncthreads();
#pragma unroll
    for (int dy = 0; dy < 32; dy += 8)
        d[(size_t)(c0 + ty + dy) * Dn + (r0 + tx)] = tile[tx][ty + dy];
}

extern "C" void kernel_launch(void* const* d_in, const int* in_sizes, int n_in,
                              void* d_out, int out_size, void* d_ws, size_t ws_size,
                              hipStream_t stream) {
    const float* x      = (const float*)d_in[0];
    const float* gamma1 = (const float*)d_in[1];
    const float* beta1  = (const float*)d_in[2];
    const float* w_q    = (const float*)d_in[3];
    const float* w_k    = (const float*)d_in[4];
    const float* w_v    = (const float*)d_in[5];
    const float* gamma2 = (const float*)d_in[6];
    const float* beta2  = (const float*)d_in[7];
    const float* W1     = (const float*)d_in[8];
    const float* b1     = (const float*)d_in[9];
    const float* W2     = (const float*)d_in[10];
    const float* b2     = (const float*)d_in[11];
    float* out = (float*)d_out;   // fp32 output buffer (compared in bf16 space)

    char* ws = (char*)d_ws;
    size_t off = 0;
    auto alloc = [&](size_t bytes) {
        char* p = ws + off;
        off += (bytes + 255) & ~(size_t)255;
        return p;
    };
    const size_t BT = (size_t)Bn * Tn;
    bf16* h    = (bf16*)alloc(BT * Dn * 2);               // 16 MB; reused as h2
    bf16* qk   = (bf16*)alloc(BT * 2 * Dn * 2);           // 32 MB [8192,2048] (q|k)
    bf16* vt   = (bf16*)alloc(BT * Dn * 2);               // 16 MB [4][1024,2048]
    bf16* wbuf = (bf16*)alloc((size_t)5 * Dn * Dn * 2);   // 10 MB (wq|wk|wv|w1|w2)^T
    bf16* S    = (bf16*)alloc((size_t)Bn * Tn * Tn * 2);  // 32 MB masked exp scores
    bf16* y    = (bf16*)alloc(BT * Dn * 2);               // 16 MB (own buffer: S live in PV!)
    bf16* h2   = h;            // h dead after QKV
    bf16* mid  = qk;           // qk dead after scores

    const dim3 blk(256);
    const long TD  = (long)Tn * Dn;
    const long TT  = (long)Tn * Tn;
    const long TD2 = (long)Tn * 2 * Dn;

    // all 5 weight transposes in one dispatch
    WPtrs wp; wp.p[0] = w_q; wp.p[1] = w_k; wp.p[2] = w_v; wp.p[3] = W1; wp.p[4] = W2;
    wtrans_kernel<<<dim3(32, 32, 5), blk, 0, stream>>>(wp, wbuf);

    // LN1: x -> h (bf16)
    ln_kernel<float><<<dim3((unsigned)BT), blk, 0, stream>>>(x, gamma1, beta1, h);

    // merged QKV: q,k -> qk (ldc=2048); v -> vt transposed via LDS
    gemm_nt<128, 128, 4, 1, bf16, float, false><<<dim3(24, 64, 1), blk, 0, stream>>>(
        h, wbuf, qk, nullptr, nullptr, vt,
        (int)BT, 3 * Dn, Dn, Dn, Dn, 2 * Dn, 0, 0, 0, 0, 0);

    // S_exp = exp(q @ k^T * scale), causal-masked, bf16 (block-skip above diag)
    gemm_nt<128, 128, 4, 2, bf16, float, false><<<dim3(16, 16, Bn), blk, 0, stream>>>(
        qk, qk + 1024, S, nullptr, nullptr, nullptr,
        Tn, Tn, Dn, 2 * Dn, 2 * Dn, Tn, TD2, TD2, TT, 0, 1);

    // y = softmax(S) @ V + x: PV with self-computed row sums, K truncated
    gemm_nt<128, 128, 4, 3, bf16, float, false><<<dim3(8, 16, Bn), blk, 0, stream>>>(
        S, vt, y, nullptr, x, nullptr,
        Tn, Dn, Tn, Tn, Tn, Dn, TT, TD, TD, TD, 2);

    // LN2: y (bf16) -> h2 (bf16)
    ln_kernel<bf16><<<dim3((unsigned)BT), blk, 0, stream>>>(y, gamma2, beta2, h2);

    // mid = relu(h2 @ W1 + b1)
    gemm_nt<128, 128, 4, 0, bf16, float, true><<<dim3(8, 64, 1), blk, 0, stream>>>(
        h2, wbuf + (size_t)3 * Dn * Dn, mid, b1, nullptr, nullptr,
        (int)BT, Dn, Dn, Dn, Dn, Dn, 0, 0, 0, 0, 0);

    // out = mid @ W2 + b2 + y (fp32 out, bf16 residual)
    gemm_nt<128, 128, 4, 0, float, bf16, false><<<dim3(8, 64, 1), blk, 0, stream>>>(
        mid, wbuf + (size_t)4 * Dn * Dn, out, b2, y, nullptr,
        (int)BT, Dn, Dn, Dn, Dn, Dn, 0, 0, 0, 0, 0);
}

// Round 8
// 348.297 us; speedup vs baseline: 1.2826x; 1.0436x over previous
//
#include <hip/hip_runtime.h>
#include <hip/hip_bf16.h>
#include <math.h>

using bf16 = __hip_bfloat16;

static constexpr int Bn = 4;
static constexpr int Tn = 2048;
static constexpr int Dn = 1024;

typedef __attribute__((ext_vector_type(8))) short bf16x8;
typedef __attribute__((ext_vector_type(4))) float f32x4;

__device__ __forceinline__ float ldf(float v) { return v; }
__device__ __forceinline__ float ldf(bf16 v) { return __bfloat162float(v); }
__device__ __forceinline__ bf16 f2b(float v) { return __float2bfloat16(v); }
__device__ __forceinline__ float b2f(short s) {
    return __uint_as_float(((unsigned)(unsigned short)s) << 16);
}
__device__ __forceinline__ short f2bs(float v) {
    bf16 t = __float2bfloat16(v);
    return *reinterpret_cast<short*>(&t);
}

template <typename T> __device__ __forceinline__ T from_float(float v);
template <> __device__ __forceinline__ float from_float<float>(float v) { return v; }
template <> __device__ __forceinline__ bf16 from_float<bf16>(float v) { return f2b(v); }

__device__ __forceinline__ void load4(const float* p, float* v) {
    const float4 t = *(const float4*)p;
    v[0] = t.x; v[1] = t.y; v[2] = t.z; v[3] = t.w;
}
__device__ __forceinline__ void load4(const bf16* p, float* v) {
    const short4 t = *(const short4*)p;
    v[0] = b2f(t.x); v[1] = b2f(t.y); v[2] = b2f(t.z); v[3] = b2f(t.w);
}

// async global->LDS, 16B per lane; LDS dest wave-uniform base, HW scatters +lane*16.
__device__ __forceinline__ void async_copy16(const bf16* g, bf16* l) {
    __builtin_amdgcn_global_load_lds(
        (const __attribute__((address_space(1))) void*)g,
        (__attribute__((address_space(3))) void*)l,
        16, 0, 0);
}

// ---------------------------------------------------------------------------
// Generic NT GEMM: C[m,n] = sum_k A[m,k]*B[n,k], bf16 inputs, explicit ld's.
// BK=64 as two BK=32 sub-stages (64 B LDS row stride, m97-validated geometry).
// 128x128 tile, 4 waves 2x2, wave tile 64x64 -> 32 MFMA per barrier pair.
// XCD swizzle: blockIdx.x = bm ALWAYS (XCD ~ linear%8 = bm%8), so blocks
// sharing an A-strip co-reside on one XCD's L2.
// mode 0: full; 1: skip blocks fully above diagonal; 2: K truncated at bm*BM+BM.
// EPI epilogue variants:
//  0: plain  (+bias, optional RELU, +res)
//  1: QKV    (cols<2048 -> C ldc=2048; cols>=2048 -> V^T via LDS into vtp)
//  2: scores (write bf16(exp(acc*scale)), causal mask; atomicAdd row sums
//             of the bf16-rounded exp values into rowsum[b][row])
//  3: PV     (epilogue scales acc by 1/rowsum[b][row], then +res)
// ---------------------------------------------------------------------------
template <int BM, int BN, int MINW, int EPI, typename OutT, typename ResT, bool RELU>
__global__ __launch_bounds__(256, MINW) void gemm_nt(
    const bf16* __restrict__ A, const bf16* __restrict__ Bm,
    OutT* __restrict__ C, const float* __restrict__ bias,
    const ResT* __restrict__ res, bf16* __restrict__ vtp,
    float* __restrict__ rowsum,
    int M, int N, int K, int lda, int ldb, int ldc,
    long sA, long sB, long sC, long sR, int mode)
{
    const int bm = blockIdx.x, bn = blockIdx.y, bz = blockIdx.z;
    if (mode == 1 && bn * BN > bm * BM + (BM - 1)) return;
    const int kend = bm * BM + BM;
    const int kmax = (mode == 2) ? (kend < K ? kend : K) : K;

    const bf16* Ab = A + (size_t)bz * sA;
    const bf16* Bb = Bm + (size_t)bz * sB;

    constexpr int WROWS = BM / 64;
    constexpr int WCOLS = 4 / WROWS;
    constexpr int TM = 64;
    constexpr int TN = BN / WCOLS;
    constexpr int MT = TM / 16;
    constexpr int NT = TN / 16;
    constexpr int nA = BM / 16;
    constexpr int nB = BN / 16;
    constexpr int TSTR = 132;   // padded LDS stride for V^T transpose (EPI==1)
    constexpr int STAGE = 2 * (BM + BN) * 32;
    constexpr int SME = (EPI == 1 && BM * TSTR > STAGE) ? BM * TSTR : STAGE;

    __shared__ __align__(16) bf16 smem[SME];
    bf16* As = smem;
    bf16* Bs = smem + 2 * BM * 32;

    const int tid = threadIdx.x;
    const int wave = tid >> 6;
    const int lane = tid & 63;
    const int wm = wave / WCOLS;
    const int wn = wave % WCOLS;

    f32x4 acc[MT][NT] = {};

    const int lr = lane >> 2;
    const int lc = (lane & 3) * 8;
    const bf16* gAc[nA / 4]; bf16* lAc[nA / 4];
    const bf16* gBc[nB / 4]; bf16* lBc[nB / 4];
#pragma unroll
    for (int i = 0; i < nA / 4; ++i) {
        const int c = wave + 4 * i;
        gAc[i] = Ab + (size_t)(bm * BM + c * 16 + lr) * lda + lc;
        lAc[i] = &As[c * 512];
    }
#pragma unroll
    for (int i = 0; i < nB / 4; ++i) {
        const int c = wave + 4 * i;
        gBc[i] = Bb + (size_t)(bn * BN + c * 16 + lr) * ldb + lc;
        lBc[i] = &Bs[c * 512];
    }

    const int arow = lane & 15;
    const int kq = (lane >> 4) * 8;

    for (int k0 = 0; k0 < kmax; k0 += 64) {
#pragma unroll
        for (int hh = 0; hh < 2; ++hh) {
#pragma unroll
            for (int i = 0; i < nA / 4; ++i)
                async_copy16(gAc[i] + k0 + 32 * hh, lAc[i] + hh * (BM * 32));
#pragma unroll
            for (int i = 0; i < nB / 4; ++i)
                async_copy16(gBc[i] + k0 + 32 * hh, lBc[i] + hh * (BN * 32));
        }
        __syncthreads();

#pragma unroll
        for (int hh = 0; hh < 2; ++hh) {
            const bf16* Ah = As + hh * (BM * 32);
            const bf16* Bh = Bs + hh * (BN * 32);
            bf16x8 af[MT], bfm[NT];
#pragma unroll
            for (int t = 0; t < MT; ++t)
                af[t] = *(const bf16x8*)&Ah[(wm * TM + t * 16 + arow) * 32 + kq];
#pragma unroll
            for (int t = 0; t < NT; ++t)
                bfm[t] = *(const bf16x8*)&Bh[(wn * TN + t * 16 + arow) * 32 + kq];
#pragma unroll
            for (int mt = 0; mt < MT; ++mt)
#pragma unroll
                for (int nt = 0; nt < NT; ++nt)
                    acc[mt][nt] = __builtin_amdgcn_mfma_f32_16x16x32_bf16(
                        af[mt], bfm[nt], acc[mt][nt], 0, 0, 0);
        }
        __syncthreads();
    }

    const int rowBase = bm * BM + wm * TM;
    const int colBase = bn * BN + wn * TN;
    const int qrow = (lane >> 4) * 4;
    const int ccol = lane & 15;

    if (EPI == 1 && bn * BN >= 2048) {
        // V columns: transpose via LDS, then coalesced writes to vt[b][d][t].
        bf16* tt = smem;   // safe: loop ended with __syncthreads()
#pragma unroll
        for (int mt = 0; mt < MT; ++mt) {
            const int tl = wm * TM + mt * 16 + qrow;
#pragma unroll
            for (int nt = 0; nt < NT; ++nt) {
                const int dl = wn * TN + nt * 16 + ccol;
                short4 o;
                o.x = f2bs(acc[mt][nt][0]);
                o.y = f2bs(acc[mt][nt][1]);
                o.z = f2bs(acc[mt][nt][2]);
                o.w = f2bs(acc[mt][nt][3]);
                *(short4*)&tt[dl * TSTR + tl] = o;
            }
        }
        __syncthreads();
        const int dl = tid >> 1;
        const int th = (tid & 1) * 64;
        const int dg = bn * BN - 2048 + dl;
        const int b = (bm * BM) >> 11;
        const int tin = (bm * BM) & (Tn - 1);
        bf16* dst = vtp + ((size_t)b * Dn + dg) * Tn + tin + th;
        const bf16* srcl = &tt[dl * TSTR + th];
#pragma unroll
        for (int i = 0; i < 16; ++i)
            ((short4*)dst)[i] = ((const short4*)srcl)[i];
        return;
    }

    if (EPI == 2) {
        // masked exp scores + atomic row sums (of the bf16-rounded values)
        OutT* Cb = C + (size_t)bz * sC;
        float* rsb = rowsum + (size_t)bz * Tn;
        const float scale = 0.03125f;
#pragma unroll
        for (int mt = 0; mt < MT; ++mt) {
            float rsv[4] = {0.f, 0.f, 0.f, 0.f};
#pragma unroll
            for (int nt = 0; nt < NT; ++nt) {
                const int cc = colBase + nt * 16 + ccol;
#pragma unroll
                for (int r = 0; r < 4; ++r) {
                    const int rr = rowBase + mt * 16 + qrow + r;
                    float e = 0.0f;
                    if (cc <= rr) {
                        const short es = f2bs(__expf(acc[mt][nt][r] * scale));
                        Cb[(size_t)rr * ldc + cc] = *(const bf16*)&es;
                        e = b2f(es);
                    } else {
                        Cb[(size_t)rr * ldc + cc] = from_float<OutT>(0.0f);
                    }
                    rsv[r] += e;
                }
            }
#pragma unroll
            for (int r = 0; r < 4; ++r) {
                float v = rsv[r];
                v += __shfl_xor(v, 1);
                v += __shfl_xor(v, 2);
                v += __shfl_xor(v, 4);
                v += __shfl_xor(v, 8);
                if (ccol == 0)
                    atomicAdd(rsb + rowBase + mt * 16 + qrow + r, v);
            }
        }
        return;
    }

    OutT* Cb = C + (size_t)bz * sC;
    const ResT* Rb = res ? (res + (size_t)bz * sR) : nullptr;
    const float* rsb = (EPI == 3) ? (rowsum + (size_t)bz * Tn) : nullptr;
#pragma unroll
    for (int mt = 0; mt < MT; ++mt) {
        float inv4[4];
        if (EPI == 3) {
#pragma unroll
            for (int r = 0; r < 4; ++r)
                inv4[r] = 1.0f / rsb[rowBase + mt * 16 + qrow + r];
        }
#pragma unroll
        for (int nt = 0; nt < NT; ++nt) {
            const int cc = colBase + nt * 16 + ccol;
            const float bv = bias ? bias[cc] : 0.0f;
#pragma unroll
            for (int r = 0; r < 4; ++r) {
                const int rr = rowBase + mt * 16 + qrow + r;
                float v = acc[mt][nt][r];
                if (EPI == 3) v *= inv4[r];
                v += bv;
                if (RELU) v = fmaxf(v, 0.0f);
                if (Rb) v += ldf(Rb[(size_t)rr * ldc + cc]);
                Cb[(size_t)rr * ldc + cc] = from_float<OutT>(v);
            }
        }
    }
}

// ---------------------------------------------------------------------------
// LayerNorm body (faithfully buggy): out = (x - mean/sqrt(var_unbiased))*g + b
// ---------------------------------------------------------------------------
template <typename InT>
__device__ __forceinline__ void ln_row(
    const InT* __restrict__ xr, const float* __restrict__ gamma,
    const float* __restrict__ beta, bf16* __restrict__ orow, int tid)
{
    const int j = tid * 4;
    float v[4];
    load4(xr + j, v);
    float s = v[0] + v[1] + v[2] + v[3];
    float sq = v[0] * v[0] + v[1] * v[1] + v[2] * v[2] + v[3] * v[3];
#pragma unroll
    for (int o = 32; o > 0; o >>= 1) {
        s += __shfl_down(s, o);
        sq += __shfl_down(sq, o);
    }
    __shared__ float red[2][4];
    const int lane = tid & 63, w = tid >> 6;
    if (lane == 0) { red[0][w] = s; red[1][w] = sq; }
    __syncthreads();
    s  = red[0][0] + red[0][1] + red[0][2] + red[0][3];
    sq = red[1][0] + red[1][1] + red[1][2] + red[1][3];
    const float mean = s / (float)Dn;
    const float var = (sq - s * s / (float)Dn) / (float)(Dn - 1);
    const float coef = mean * rsqrtf(var);

    const float4 g = *(const float4*)(gamma + j);
    const float4 be = *(const float4*)(beta + j);
    short4 o;
    o.x = f2bs((v[0] - coef) * g.x + be.x);
    o.y = f2bs((v[1] - coef) * g.y + be.y);
    o.z = f2bs((v[2] - coef) * g.z + be.z);
    o.w = f2bs((v[3] - coef) * g.w + be.w);
    *(short4*)(orow + j) = o;
}

template <typename InT>
__global__ __launch_bounds__(256) void ln_kernel(
    const InT* __restrict__ x, const float* __restrict__ gamma,
    const float* __restrict__ beta, bf16* __restrict__ out)
{
    const int row = blockIdx.x;
    ln_row(x + (size_t)row * Dn, gamma, beta, out + (size_t)row * Dn, threadIdx.x);
}

// ---------------------------------------------------------------------------
// Fused prep: [0,5120) weight transposes (5 x 1024^2, fp32->bf16),
// [5120,5128) zero rowsum, [5128,13320) LN1 rows.
// ---------------------------------------------------------------------------
struct WPtrs { const float* p[5]; };

__global__ __launch_bounds__(256) void prep_kernel(
    WPtrs wp, bf16* __restrict__ wdst, float* __restrict__ rowsum,
    const float* __restrict__ x, const float* __restrict__ gamma1,
    const float* __restrict__ beta1, bf16* __restrict__ h)
{
    const int bx = blockIdx.x;
    if (bx < 5120) {
        __shared__ bf16 tile[32][33];
        const int z = bx >> 10;
        const int t = bx & 1023;
        const float* src = wp.p[z];
        bf16* d = wdst + (size_t)z * Dn * Dn;
        const int c0 = (t & 31) * 32, r0 = (t >> 5) * 32;
        const int tx = threadIdx.x & 31;
        const int ty = threadIdx.x >> 5;
#pragma unroll
        for (int dy = 0; dy < 32; dy += 8)
            tile[ty + dy][tx] = f2b(src[(size_t)(r0 + ty + dy) * Dn + (c0 + tx)]);
        __syncthreads();
#pragma unroll
        for (int dy = 0; dy < 32; dy += 8)
            d[(size_t)(c0 + ty + dy) * Dn + (r0 + tx)] = tile[tx][ty + dy];
    } else if (bx < 5128) {
        const int idx = (bx - 5120) * 1024 + (int)threadIdx.x;
        // 8 blocks x 1024? blockDim=256 -> cover 8192 floats with 4 per thread
        const int base = (bx - 5120) * 1024;
#pragma unroll
        for (int i = 0; i < 4; ++i) rowsum[base + i * 256 + threadIdx.x] = 0.0f;
        (void)idx;
    } else {
        const int row = bx - 5128;
        ln_row(x + (size_t)row * Dn, gamma1, beta1, h + (size_t)row * Dn, threadIdx.x);
    }
}

extern "C" void kernel_launch(void* const* d_in, const int* in_sizes, int n_in,
                              void* d_out, int out_size, void* d_ws, size_t ws_size,
                              hipStream_t stream) {
    const float* x      = (const float*)d_in[0];
    const float* gamma1 = (const float*)d_in[1];
    const float* beta1  = (const float*)d_in[2];
    const float* w_q    = (const float*)d_in[3];
    const float* w_k    = (const float*)d_in[4];
    const float* w_v    = (const float*)d_in[5];
    const float* gamma2 = (const float*)d_in[6];
    const float* beta2  = (const float*)d_in[7];
    const float* W1     = (const float*)d_in[8];
    const float* b1     = (const float*)d_in[9];
    const float* W2     = (const float*)d_in[10];
    const float* b2     = (const float*)d_in[11];
    float* out = (float*)d_out;   // fp32 output buffer (compared in bf16 space)

    char* ws = (char*)d_ws;
    size_t off = 0;
    auto alloc = [&](size_t bytes) {
        char* p = ws + off;
        off += (bytes + 255) & ~(size_t)255;
        return p;
    };
    const size_t BT = (size_t)Bn * Tn;
    bf16* h    = (bf16*)alloc(BT * Dn * 2);               // 16 MB; reused as h2
    bf16* qk   = (bf16*)alloc(BT * 2 * Dn * 2);           // 32 MB [8192,2048] (q|k)
    bf16* vt   = (bf16*)alloc(BT * Dn * 2);               // 16 MB [4][1024,2048]
    bf16* wbuf = (bf16*)alloc((size_t)5 * Dn * Dn * 2);   // 10 MB (wq|wk|wv|w1|w2)^T
    bf16* S    = (bf16*)alloc((size_t)Bn * Tn * Tn * 2);  // 32 MB masked exp scores
    bf16* y    = (bf16*)alloc(BT * Dn * 2);               // 16 MB
    float* rowsum = (float*)alloc((size_t)Bn * Tn * 4);   // 32 KB
    bf16* h2   = h;            // h dead after QKV
    bf16* mid  = qk;           // qk dead after scores

    const dim3 blk(256);
    const long TD  = (long)Tn * Dn;
    const long TT  = (long)Tn * Tn;
    const long TD2 = (long)Tn * 2 * Dn;

    // fused: 5 weight transposes + rowsum zero + LN1
    WPtrs wp; wp.p[0] = w_q; wp.p[1] = w_k; wp.p[2] = w_v; wp.p[3] = W1; wp.p[4] = W2;
    prep_kernel<<<dim3(5128 + (unsigned)BT, 1, 1), blk, 0, stream>>>(
        wp, wbuf, rowsum, x, gamma1, beta1, h);

    // merged QKV: q,k -> qk (ldc=2048); v -> vt transposed via LDS. grid (bm, bn)
    gemm_nt<128, 128, 4, 1, bf16, float, false><<<dim3(64, 24, 1), blk, 0, stream>>>(
        h, wbuf, qk, nullptr, nullptr, vt, nullptr,
        (int)BT, 3 * Dn, Dn, Dn, Dn, 2 * Dn, 0, 0, 0, 0, 0);

    // S_exp = exp(q @ k^T * scale) causal-masked + atomic row sums
    gemm_nt<128, 128, 4, 2, bf16, float, false><<<dim3(16, 16, Bn), blk, 0, stream>>>(
        qk, qk + 1024, S, nullptr, nullptr, nullptr, rowsum,
        Tn, Tn, Dn, 2 * Dn, 2 * Dn, Tn, TD2, TD2, TT, 0, 1);

    // y = (S_exp @ V) / rowsum + x : clean GEMM, K truncated at diagonal
    gemm_nt<128, 128, 4, 3, bf16, float, false><<<dim3(16, 8, Bn), blk, 0, stream>>>(
        S, vt, y, nullptr, x, nullptr, rowsum,
        Tn, Dn, Tn, Tn, Tn, Dn, TT, TD, TD, TD, 2);

    // LN2: y (bf16) -> h2 (bf16)
    ln_kernel<bf16><<<dim3((unsigned)BT), blk, 0, stream>>>(y, gamma2, beta2, h2);

    // mid = relu(h2 @ W1 + b1)
    gemm_nt<128, 128, 4, 0, bf16, float, true><<<dim3(64, 8, 1), blk, 0, stream>>>(
        h2, wbuf + (size_t)3 * Dn * Dn, mid, b1, nullptr, nullptr, nullptr,
        (int)BT, Dn, Dn, Dn, Dn, Dn, 0, 0, 0, 0, 0);

    // out = mid @ W2 + b2 + y (fp32 out, bf16 residual)
    gemm_nt<128, 128, 4, 0, float, bf16, false><<<dim3(64, 8, 1), blk, 0, stream>>>(
        mid, wbuf + (size_t)4 * Dn * Dn, out, b2, y, nullptr, nullptr,
        (int)BT, Dn, Dn, Dn, Dn, Dn, 0, 0, 0, 0, 0);
}